// Round 21
// baseline (392.306 us; speedup 1.0000x reference)
//
#include <hip/hip_runtime.h>
#include <math.h>

#define NB 128            // graphs
#define NN 1024           // nodes per graph
#define BNODES (NB*NN)    // 131072
#define NE 2097152        // edges
#define EPG (NE/NB)       // 16384 edges per graph (edge list is graph-blocked)
#define EPT (EPG/NN)      // 16 edges per thread in k_csr
#define FH 64             // hidden
#define KK1 820
#define KK2 656
#define KK3 525

// ---------------- one-kernel CSR build + layer-1 degrees ----------------
__global__ __launch_bounds__(1024) void k_csr(const int* __restrict__ ei,
                                              const float* __restrict__ ea,
                                              int* __restrict__ rowptr,
                                              int2* __restrict__ csr_sw,
                                              float* __restrict__ dinvW,
                                              float* __restrict__ dinvU) {
  extern __shared__ int2 lcsr[];          // EPG entries = 128 KB
  __shared__ int cnt[NN];
  __shared__ int cur[NN];
  __shared__ float wsum[NN];
  int b = blockIdx.x, t = threadIdx.x;
  int node = b*NN + t;
  cnt[t] = 0;
  wsum[t] = 0.f;
  __syncthreads();
  int ebase = b*EPG;
  int se[EPT]; int de[EPT]; float we[EPT];
  #pragma unroll
  for (int i = 0; i < EPT; ++i) {
    int e = ebase + i*NN + t;
    se[i] = ei[e];
    de[i] = ei[NE + e] - b*NN;
    we[i] = ea[e];
    atomicAdd(&cnt[de[i]], 1);
    atomicAdd(&wsum[de[i]], we[i]);
  }
  __syncthreads();
  int v = cnt[t];
  for (int off = 1; off < NN; off <<= 1) {
    int u = (t >= off) ? cnt[t - off] : 0;
    __syncthreads();
    cnt[t] += u;
    __syncthreads();
  }
  int excl = cnt[t] - v;
  rowptr[node] = ebase + excl;
  cur[t] = excl;
  dinvW[node] = rsqrtf(1.f + wsum[t]);    // layer-1 weighted degree (all alive)
  dinvU[node] = rsqrtf(1.f + (float)v);   // layer-1 unweighted degree
  if (b == NB-1 && t == NN-1) rowptr[BNODES] = NE;
  __syncthreads();
  #pragma unroll
  for (int i = 0; i < EPT; ++i) {
    int pos = atomicAdd(&cur[de[i]], 1);
    lcsr[pos] = make_int2(se[i], __float_as_int(we[i]));
  }
  __syncthreads();
  float4* dst4 = (float4*)(csr_sw + ebase);
  const float4* src4 = (const float4*)lcsr;
  #pragma unroll
  for (int i = 0; i < EPG/2/NN; ++i)
    dst4[i*NN + t] = src4[i*NN + t];
}

// ---------------- per-edge coefficient: cei[e] = (src, dinvW[src]*w) ----------------
// MODE 0/1: w = ea (dead src -> dinvW=0 masks). MODE 2: w = 1.
template<int MODE>
__global__ void k_coef(const int2* __restrict__ csr_sw, const float* __restrict__ dinvW,
                       int2* __restrict__ cei) {
  int e = blockIdx.x*256 + threadIdx.x;
  if (e >= NE) return;
  int2 p = csr_sw[e];
  float w = (MODE == 2) ? 1.f : __int_as_float(p.y);
  cei[e] = make_int2(p.x, __float_as_int(dinvW[p.x] * w));
}

// ---------------- LDS-staged GCN gather: 1 block per (graph, feature-QUARTER) ----------------
// blockIdx = quarter*NB + b  -> all 4 slices of graph b on XCD b%8 (csr/cei once/XCD).
// Inner loop: group-uniform cei load + ds_read_b128 + fma. No shfl, no sDW.
template<int MODE, bool L1S>
__global__ __launch_bounds__(1024, 8) void k_gath(
    const int* __restrict__ rowptr, const int2* __restrict__ cei,
    const float* __restrict__ dinvW, const float* __restrict__ src,  // hBq or x
    const float* __restrict__ Wl,                                    // W1 (L1S only)
    const float* __restrict__ bias, const float* __restrict__ Wp,
    float* __restrict__ hA, float* __restrict__ qpart) {
  extern __shared__ float sHB[];        // [NN][16] = 64 KB
  __shared__ float sWp[16];
  __shared__ float sB[16];
  __shared__ float sW1[32];
  int b = blockIdx.x & (NB-1), quarter = blockIdx.x >> 7;
  int t = threadIdx.x, l4 = t & 3;
  int gbase = b*NN;
  if (t < 16) { sWp[t] = Wp[quarter*16 + t]; sB[t] = bias[quarter*16 + t]; }
  float4* sHB4 = (float4*)sHB;
  if (L1S) {
    if (t < 16) { sW1[t] = Wl[quarter*16 + t]; sW1[16 + t] = Wl[64 + quarter*16 + t]; }
    __syncthreads();
    #pragma unroll
    for (int i = 0; i < 16; ++i) {
      int el = i*1024 + t;               // 16384 floats
      int n = el >> 4, ff = el & 15;
      float x0 = src[(size_t)(gbase + n)*2];
      float x1 = src[(size_t)(gbase + n)*2 + 1];
      sHB[n*16 + ff] = x0*sW1[ff] + x1*sW1[16 + ff];
    }
  } else {
    const float4* hq4 = (const float4*)src + (size_t)quarter*BNODES*4 + (size_t)gbase*4;
    #pragma unroll
    for (int i = 0; i < 4; ++i) {
      int idx = i*1024 + t;              // 4096 float4 = 64 KB
      sHB4[idx] = hq4[idx];
    }
  }
  __syncthreads();
  float4 bv = ((const float4*)sB)[l4];
  float4 wp = ((const float4*)sWp)[l4];
  #pragma unroll 1
  for (int pass = 0; pass < 4; ++pass) {
    int n = pass*256 + (t >> 2);
    int gn = gbase + n;
    float dd = dinvW[gn];
    float4 hv = sHB4[n*4 + l4];
    float dd2 = dd*dd;
    float4 acc;
    acc.x = fmaf(dd2, hv.x, bv.x);
    acc.y = fmaf(dd2, hv.y, bv.y);
    acc.z = fmaf(dd2, hv.z, bv.z);
    acc.w = fmaf(dd2, hv.w, bv.w);
    int r0 = rowptr[gn], r1 = rowptr[gn+1];
    for (int e = r0; e < r1; ++e) {
      int2 p = cei[e];                   // group-uniform (4 lanes same addr)
      float c = dd * __int_as_float(p.y);
      float4 v = sHB4[(p.x - gbase)*4 + l4];
      acc.x = fmaf(c, v.x, acc.x);
      acc.y = fmaf(c, v.y, acc.y);
      acc.z = fmaf(c, v.z, acc.z);
      acc.w = fmaf(c, v.w, acc.w);
    }
    acc.x = fmaxf(acc.x, 0.f); acc.y = fmaxf(acc.y, 0.f);
    acc.z = fmaxf(acc.z, 0.f); acc.w = fmaxf(acc.w, 0.f);
    ((float4*)hA)[(size_t)quarter*BNODES*4 + (size_t)gn*4 + l4] = acc;  // quarter-major
    float dot = acc.x*wp.x + acc.y*wp.y + acc.z*wp.z + acc.w*wp.w;
    dot += __shfl_xor(dot, 2, 4);
    dot += __shfl_xor(dot, 1, 4);
    if (l4 == 0) qpart[quarter*BNODES + gn] = dot;
  }
}

// ---------------- q finalize: q = dinvU * (qp0+qp1+qp2+qp3) ----------------
__global__ void k_qfin(const float* __restrict__ dinvU, const float* __restrict__ qp,
                       float* __restrict__ q) {
  int i = blockIdx.x*256 + threadIdx.x;
  if (i < BNODES)
    q[i] = dinvU[i]*(qp[i] + qp[BNODES + i] + qp[2*BNODES + i] + qp[3*BNODES + i]);
}

// ---------------- scoring aggregation (q self-masking, full grid) ----------------
__global__ void k_score(const int* __restrict__ rowptr, const int2* __restrict__ csr_sw,
                        const float* __restrict__ dinvU, const float* __restrict__ q,
                        const float* __restrict__ bp, float* __restrict__ score) {
  int t = threadIdx.x;
  int l16 = t & 15;
  int d = blockIdx.x*16 + (t >> 4);
  float du = dinvU[d];
  float sum = 0.f;
  if (du != 0.f) {
    int r0 = rowptr[d], r1 = rowptr[d+1];
    for (int base = r0; base < r1; base += 16)
      if (base + l16 < r1) sum += q[csr_sw[base + l16].x];
  }
  #pragma unroll
  for (int off = 8; off; off >>= 1) sum += __shfl_xor(sum, off, 16);
  if (l16 == 0) score[d] = bp[0] + du*(q[d] + sum);
}

// ---------------- top-k rank: 4 blocks/graph; alive test = dinvU != 0 ----------------
__global__ void k_topk(const float* __restrict__ score,
                       const float* __restrict__ dinvU, int k,
                       float* __restrict__ tm, int* __restrict__ aliveN) {
  __shared__ float sc[NN];
  int b = blockIdx.x >> 2, p = blockIdx.x & 3;
  int t = threadIdx.x;
  int gbase = b*NN;
  #pragma unroll
  for (int i = 0; i < 4; ++i) {
    int n = i*256 + t;
    sc[n] = (dinvU[gbase + n] != 0.f) ? score[gbase + n] : -INFINITY;
  }
  __syncthreads();
  int n = p*256 + t;              // this thread's node
  int node = gbase + n;
  float me = sc[n];
  float raw = score[node];
  int rank = 0;
  const float4* sc4 = (const float4*)sc;
  for (int j4 = 0; j4 < NN/4; ++j4) {
    float4 o = sc4[j4];
    int jb = j4*4;
    rank += (o.x > me) || (o.x == me && jb+0 < n);
    rank += (o.y > me) || (o.y == me && jb+1 < n);
    rank += (o.z > me) || (o.z == me && jb+2 < n);
    rank += (o.w > me) || (o.w == me && jb+3 < n);
  }
  int sel = (rank < k) ? 1 : 0;
  aliveN[node] = sel;
  tm[node] = sel ? tanhf(raw) : 0.f;
}

// ---------------- degrees (next layer): 16-lane group per node, full grid ----------------
template<int MODE>
__global__ void k_degs(const int* __restrict__ rowptr, const int2* __restrict__ csr_sw,
                       const int* __restrict__ alive,
                       float* __restrict__ dinvW, float* __restrict__ dinvU) {
  int t = threadIdx.x;
  int l16 = t & 15;
  int d = blockIdx.x*16 + (t >> 4);
  int r0 = rowptr[d], r1 = rowptr[d+1];
  float sW = 0.f, sU = 0.f;
  for (int base = r0; base < r1; base += 16) {
    if (base + l16 < r1) {
      int2 p = csr_sw[base + l16];
      if (alive[p.x]) { sW += (MODE == 2) ? 1.f : __int_as_float(p.y); sU += 1.f; }
    }
  }
  #pragma unroll
  for (int off = 8; off; off >>= 1) {
    sW += __shfl_xor(sW, off, 16);
    sU += __shfl_xor(sU, off, 16);
  }
  if (l16 == 0) {
    bool dA = (alive[d] != 0);
    dinvW[d] = dA ? rsqrtf(1.f + sW) : 0.f;
    dinvU[d] = dA ? rsqrtf(1.f + sU) : 0.f;
  }
}

// ---------------- fused readout partials (+ optional pool-scale @ W) ----------------
// hA read quarter-major; hB written quarter-major.
template<bool DOLIN>
__global__ void k_srl(const float* __restrict__ hA, const float* __restrict__ tm,
                      const int* __restrict__ aliveN, const float* __restrict__ W,
                      float* __restrict__ hB,
                      float* __restrict__ pmax, float* __restrict__ psum) {
  __shared__ float sX[64][65];
  __shared__ float sW[64*64];
  __shared__ float sTm[64];
  __shared__ int sAl[64];
  __shared__ float rm[4][FH], rs[4][FH];
  int t = threadIdx.x;
  int blk = blockIdx.x;
  int nb = blk*64;
  if (DOLIN)
    for (int i = t; i < 1024; i += 256) ((float4*)sW)[i] = ((const float4*)W)[i];
  if (t < 64) { sTm[t] = tm[nb + t]; sAl[t] = aliveN[nb + t]; }
  __syncthreads();
  // stage sX = tm * hA (quarter-major source)
  #pragma unroll
  for (int q = 0; q < 4; ++q) {
    const float* hq = hA + (size_t)q*BNODES*16 + (size_t)nb*16;
    #pragma unroll
    for (int i = 0; i < 4; ++i) {
      int idx = i*256 + t;          // 1024 floats = 64 nodes x 16
      int n = idx >> 4, ff = idx & 15;
      sX[n][q*16 + ff] = hq[idx] * sTm[n];
    }
  }
  __syncthreads();
  {
    int f = t & 63, r = t >> 6;
    float mx = -INFINITY, sm = 0.f;
    #pragma unroll
    for (int i = 0; i < 16; ++i) {
      int n = r + i*4;
      float v = sX[n][f];
      if (sAl[n]) { mx = fmaxf(mx, v); sm += v; }
    }
    rm[r][f] = mx; rs[r][f] = sm;
  }
  __syncthreads();
  if (t < FH) {
    float m2 = fmaxf(fmaxf(rm[0][t], rm[1][t]), fmaxf(rm[2][t], rm[3][t]));
    float s2 = rs[0][t] + rs[1][t] + rs[2][t] + rs[3][t];
    pmax[blk*FH + t] = m2;
    psum[blk*FH + t] = s2;
  }
  if (DOLIN) {
    int node = t >> 2;
    int quarter = t & 3;
    int f0 = quarter * 16;
    float4 a0 = {0,0,0,0}, a1 = a0, a2 = a0, a3 = a0;
    #pragma unroll 4
    for (int k = 0; k < 64; ++k) {
      float xv = sX[node][k];
      const float4 w0 = *(const float4*)&sW[k*64 + f0];
      const float4 w1 = *(const float4*)&sW[k*64 + f0 + 4];
      const float4 w2 = *(const float4*)&sW[k*64 + f0 + 8];
      const float4 w3 = *(const float4*)&sW[k*64 + f0 + 12];
      a0.x = fmaf(xv, w0.x, a0.x); a0.y = fmaf(xv, w0.y, a0.y);
      a0.z = fmaf(xv, w0.z, a0.z); a0.w = fmaf(xv, w0.w, a0.w);
      a1.x = fmaf(xv, w1.x, a1.x); a1.y = fmaf(xv, w1.y, a1.y);
      a1.z = fmaf(xv, w1.z, a1.z); a1.w = fmaf(xv, w1.w, a1.w);
      a2.x = fmaf(xv, w2.x, a2.x); a2.y = fmaf(xv, w2.y, a2.y);
      a2.z = fmaf(xv, w2.z, a2.z); a2.w = fmaf(xv, w2.w, a2.w);
      a3.x = fmaf(xv, w3.x, a3.x); a3.y = fmaf(xv, w3.y, a3.y);
      a3.z = fmaf(xv, w3.z, a3.z); a3.w = fmaf(xv, w3.w, a3.w);
    }
    // quarter-major hB write: [quarter][node][16]
    float4* dst = (float4*)(hB + (size_t)quarter*BNODES*16 + (size_t)(nb + node)*16);
    dst[0] = a0; dst[1] = a1; dst[2] = a2; dst[3] = a3;
  }
}

// ---------------- partial reduce + MLP head + log_softmax ----------------
__global__ void k_mlp(const float* __restrict__ pmax, const float* __restrict__ psum,
                      const float* __restrict__ Wl1, const float* __restrict__ bl1,
                      const float* __restrict__ Wl2, const float* __restrict__ bl2,
                      const float* __restrict__ Wl3, const float* __restrict__ bl3,
                      float* __restrict__ out) {
  __shared__ float sg[2*FH];
  __shared__ float l1[FH];
  __shared__ float l2[FH/2];
  __shared__ float l3[2];
  int b = blockIdx.x, t = threadIdx.x;
  const float kf[3] = {(float)KK1, (float)KK2, (float)KK3};
  float gm = 0.f, gs = 0.f;
  #pragma unroll
  for (int l = 0; l < 3; ++l) {
    const float* pm = pmax + (size_t)l*NB*16*FH + (b*16)*FH;
    const float* ps = psum + (size_t)l*NB*16*FH + (b*16)*FH;
    float mm = -INFINITY, ss = 0.f;
    #pragma unroll
    for (int p = 0; p < 16; ++p) {
      mm = fmaxf(mm, pm[p*FH + t]);
      ss += ps[p*FH + t];
    }
    gm += mm;
    gs += ss / kf[l];
  }
  sg[t] = gm;
  sg[FH + t] = gs;
  __syncthreads();
  float acc = bl1[t];
  #pragma unroll
  for (int k = 0; k < 2*FH; ++k) acc = fmaf(sg[k], Wl1[k*FH + t], acc);
  l1[t] = fmaxf(acc, 0.f);
  __syncthreads();
  if (t < 32) {
    float a2 = bl2[t];
    #pragma unroll
    for (int k = 0; k < FH; ++k) a2 = fmaf(l1[k], Wl2[k*32 + t], a2);
    l2[t] = fmaxf(a2, 0.f);
  }
  __syncthreads();
  if (t < 2) {
    float a3 = bl3[t];
    #pragma unroll
    for (int k = 0; k < 32; ++k) a3 = fmaf(l2[k], Wl3[k*2 + t], a3);
    l3[t] = a3;
  }
  __syncthreads();
  if (t == 0) {
    float m = fmaxf(l3[0], l3[1]);
    float lse = m + logf(expf(l3[0]-m) + expf(l3[1]-m));
    out[b*2+0] = l3[0] - lse;
    out[b*2+1] = l3[1] - lse;
  }
}

extern "C" void kernel_launch(void* const* d_in, const int* in_sizes, int n_in,
                              void* d_out, int out_size, void* d_ws, size_t ws_size,
                              hipStream_t stream) {
  const float* x   = (const float*)d_in[0];
  const float* ea  = (const float*)d_in[1];
  const float* W1  = (const float*)d_in[2];
  const float* b1  = (const float*)d_in[3];
  const float* Wp1 = (const float*)d_in[4];
  const float* bp1 = (const float*)d_in[5];
  const float* W2  = (const float*)d_in[6];
  const float* b2  = (const float*)d_in[7];
  const float* Wp2 = (const float*)d_in[8];
  const float* bp2 = (const float*)d_in[9];
  const float* W3  = (const float*)d_in[10];
  const float* b3  = (const float*)d_in[11];
  const float* Wp3 = (const float*)d_in[12];
  const float* bp3 = (const float*)d_in[13];
  const float* Wl1 = (const float*)d_in[14];
  const float* bl1 = (const float*)d_in[15];
  const float* Wl2 = (const float*)d_in[16];
  const float* bl2 = (const float*)d_in[17];
  const float* Wl3 = (const float*)d_in[18];
  const float* bl3 = (const float*)d_in[19];
  const int*   ei  = (const int*)d_in[20];
  float* out = (float*)d_out;

  int2* csr_sw = (int2*)d_ws;                        // NE
  int2* cei    = csr_sw + NE;                        // NE (per-layer edge coef)
  float* hA    = (float*)(cei + NE);                 // BNODES*FH (quarter-major)
  float* hB    = hA + (size_t)BNODES*FH;             // BNODES*FH (quarter-major)
  float* dinvW = hB + (size_t)BNODES*FH;             // BNODES
  float* dinvU = dinvW + BNODES;                     // BNODES
  float* qpart = dinvU + BNODES;                     // 4*BNODES
  float* q     = qpart + 4*BNODES;                   // BNODES
  float* score = q + BNODES;                         // BNODES
  float* tm    = score + BNODES;                     // BNODES
  float* pmax  = tm + BNODES;                        // 3*NB*16*FH
  float* psum  = pmax + 3*NB*16*FH;                  // 3*NB*16*FH
  int* aliveN  = (int*)(psum + 3*NB*16*FH);          // BNODES
  int* rowptr  = aliveN + BNODES;                    // BNODES+1

  const size_t gathLds = (size_t)NN*16*sizeof(float);   // 64 KB
  const int gS = BNODES/64;                             // 2048 srl blocks
  const int gG = BNODES/16;                             // 8192 score/degs blocks
  const int gN = BNODES/256;                            // 512
  const int gE = NE/256;                                // 8192 coef blocks

  k_csr<<<NB, 1024, EPG*sizeof(int2), stream>>>(ei, ea, rowptr, csr_sw, dinvW, dinvU);

  // ===== Layer 1 =====
  k_coef<0><<<gE, 256, 0, stream>>>(csr_sw, dinvW, cei);
  k_gath<0,true><<<NB*4, 1024, gathLds, stream>>>(rowptr, cei, dinvW, x, W1, b1, Wp1, hA, qpart);
  k_qfin<<<gN, 256, 0, stream>>>(dinvU, qpart, q);
  k_score<<<gG, 256, 0, stream>>>(rowptr, csr_sw, dinvU, q, bp1, score);
  k_topk<<<NB*4, 256, 0, stream>>>(score, dinvU, KK1, tm, aliveN);
  k_srl<true><<<gS, 256, 0, stream>>>(hA, tm, aliveN, W2, hB, pmax, psum);
  k_degs<1><<<gG, 256, 0, stream>>>(rowptr, csr_sw, aliveN, dinvW, dinvU);

  // ===== Layer 2 =====
  k_coef<1><<<gE, 256, 0, stream>>>(csr_sw, dinvW, cei);
  k_gath<1,false><<<NB*4, 1024, gathLds, stream>>>(rowptr, cei, dinvW, hB, W1, b2, Wp2, hA, qpart);
  k_qfin<<<gN, 256, 0, stream>>>(dinvU, qpart, q);
  k_score<<<gG, 256, 0, stream>>>(rowptr, csr_sw, dinvU, q, bp2, score);
  k_topk<<<NB*4, 256, 0, stream>>>(score, dinvU, KK2, tm, aliveN);
  k_srl<true><<<gS, 256, 0, stream>>>(hA, tm, aliveN, W3, hB, pmax + NB*16*FH, psum + NB*16*FH);
  k_degs<2><<<gG, 256, 0, stream>>>(rowptr, csr_sw, aliveN, dinvW, dinvU);

  // ===== Layer 3 =====
  k_coef<2><<<gE, 256, 0, stream>>>(csr_sw, dinvW, cei);
  k_gath<2,false><<<NB*4, 1024, gathLds, stream>>>(rowptr, cei, dinvW, hB, W1, b3, Wp3, hA, qpart);
  k_qfin<<<gN, 256, 0, stream>>>(dinvU, qpart, q);
  k_score<<<gG, 256, 0, stream>>>(rowptr, csr_sw, dinvU, q, bp3, score);
  k_topk<<<NB*4, 256, 0, stream>>>(score, dinvU, KK3, tm, aliveN);
  k_srl<false><<<gS, 256, 0, stream>>>(hA, tm, aliveN, W3, hB, pmax + 2*NB*16*FH, psum + 2*NB*16*FH);

  k_mlp<<<NB, FH, 0, stream>>>(pmax, psum, Wl1, bl1, Wl2, bl2, Wl3, bl3, out);
}

// Round 22
// 388.216 us; speedup vs baseline: 1.0105x; 1.0105x over previous
//
#include <hip/hip_runtime.h>
#include <math.h>

#define NB 128            // graphs
#define NN 1024           // nodes per graph
#define BNODES (NB*NN)    // 131072
#define NE 2097152        // edges
#define EPG (NE/NB)       // 16384 edges per graph (edge list is graph-blocked)
#define EPT (EPG/NN)      // 16 edges per thread in k_csr
#define FH 64             // hidden
#define KK1 820
#define KK2 656
#define KK3 525

// ---------------- CSR build + layer-1 degrees + degree-sorted perm ----------------
__global__ __launch_bounds__(1024) void k_csr(const int* __restrict__ ei,
                                              const float* __restrict__ ea,
                                              int* __restrict__ rowptr,
                                              int2* __restrict__ csr_sw,
                                              float* __restrict__ dinvW,
                                              float* __restrict__ dinvU,
                                              int* __restrict__ perm) {
  extern __shared__ int2 lcsr[];          // EPG entries = 128 KB
  __shared__ int cnt[NN];
  __shared__ int cur[NN];
  __shared__ float wsum[NN];
  __shared__ int hist[64];
  int b = blockIdx.x, t = threadIdx.x;
  int node = b*NN + t;
  cnt[t] = 0;
  wsum[t] = 0.f;
  if (t < 64) hist[t] = 0;
  __syncthreads();
  int ebase = b*EPG;
  int se[EPT]; int de[EPT]; float we[EPT];
  #pragma unroll
  for (int i = 0; i < EPT; ++i) {
    int e = ebase + i*NN + t;
    se[i] = ei[e];
    de[i] = ei[NE + e] - b*NN;
    we[i] = ea[e];
    atomicAdd(&cnt[de[i]], 1);
    atomicAdd(&wsum[de[i]], we[i]);
  }
  __syncthreads();
  int v = cnt[t];
  for (int off = 1; off < NN; off <<= 1) {
    int u = (t >= off) ? cnt[t - off] : 0;
    __syncthreads();
    cnt[t] += u;
    __syncthreads();
  }
  int excl = cnt[t] - v;
  rowptr[node] = ebase + excl;
  cur[t] = excl;
  dinvW[node] = rsqrtf(1.f + wsum[t]);    // layer-1 weighted degree (all alive)
  dinvU[node] = rsqrtf(1.f + (float)v);   // layer-1 unweighted degree
  if (b == NB-1 && t == NN-1) rowptr[BNODES] = NE;
  // degree counting-sort -> perm (nodes of similar degree adjacent)
  int db = min(v, 63);
  atomicAdd(&hist[db], 1);
  __syncthreads();
  if (t == 0) {
    int run = 0;
    for (int i = 0; i < 64; ++i) { int h = hist[i]; hist[i] = run; run += h; }
  }
  __syncthreads();
  int spos = atomicAdd(&hist[db], 1);
  perm[b*NN + spos] = t;
  __syncthreads();
  #pragma unroll
  for (int i = 0; i < EPT; ++i) {
    int pos = atomicAdd(&cur[de[i]], 1);
    lcsr[pos] = make_int2(se[i], __float_as_int(we[i]));
  }
  __syncthreads();
  float4* dst4 = (float4*)(csr_sw + ebase);
  const float4* src4 = (const float4*)lcsr;
  #pragma unroll
  for (int i = 0; i < EPG/2/NN; ++i)
    dst4[i*NN + t] = src4[i*NN + t];
}

// ---------------- LDS-staged GCN gather: 1 block per (graph, feature-QUARTER) ----------------
// blockIdx = quarter*NB + b -> all 4 slices of graph b co-located per XCD.
// Nodes processed in degree-sorted order (perm) -> minimal wave divergence.
// Per edge: 1 uniform csr load + 1 sDW read + 1 ds_read_b128 + 4 fma. No shfl.
template<int MODE, bool L1S>
__global__ __launch_bounds__(1024, 8) void k_gath(
    const int* __restrict__ rowptr, const int2* __restrict__ csr_sw,
    const int* __restrict__ perm,
    const float* __restrict__ dinvW, const float* __restrict__ src,  // hBq or x
    const float* __restrict__ Wl,                                    // W1 (L1S only)
    const float* __restrict__ bias, const float* __restrict__ Wp,
    float* __restrict__ hA, float* __restrict__ qpart) {
  extern __shared__ float sHB[];        // [NN][16] = 64 KB
  __shared__ float sDW[NN];
  __shared__ float sWp[16];
  __shared__ float sB[16];
  __shared__ float sW1[32];
  int b = blockIdx.x & (NB-1), quarter = blockIdx.x >> 7;
  int t = threadIdx.x, l4 = t & 3;
  int gbase = b*NN;
  sDW[t] = dinvW[gbase + t];
  if (t < 16) { sWp[t] = Wp[quarter*16 + t]; sB[t] = bias[quarter*16 + t]; }
  float4* sHB4 = (float4*)sHB;
  if (L1S) {
    if (t < 16) { sW1[t] = Wl[quarter*16 + t]; sW1[16 + t] = Wl[64 + quarter*16 + t]; }
    __syncthreads();
    #pragma unroll
    for (int i = 0; i < 16; ++i) {
      int el = i*1024 + t;               // 16384 floats
      int n = el >> 4, ff = el & 15;
      float x0 = src[(size_t)(gbase + n)*2];
      float x1 = src[(size_t)(gbase + n)*2 + 1];
      sHB[n*16 + ff] = x0*sW1[ff] + x1*sW1[16 + ff];
    }
  } else {
    const float4* hq4 = (const float4*)src + (size_t)quarter*BNODES*4 + (size_t)gbase*4;
    #pragma unroll
    for (int i = 0; i < 4; ++i) {
      int idx = i*1024 + t;              // 4096 float4 = 64 KB
      sHB4[idx] = hq4[idx];
    }
  }
  __syncthreads();
  float4 bv = ((const float4*)sB)[l4];
  float4 wp = ((const float4*)sWp)[l4];
  #pragma unroll 1
  for (int pass = 0; pass < 4; ++pass) {
    int nl = perm[gbase + pass*256 + (t >> 2)];     // degree-sorted node
    int gn = gbase + nl;
    float dd = sDW[nl];
    float4 hv = sHB4[nl*4 + l4];
    float dd2 = dd*dd;
    float4 acc;
    acc.x = fmaf(dd2, hv.x, bv.x);
    acc.y = fmaf(dd2, hv.y, bv.y);
    acc.z = fmaf(dd2, hv.z, bv.z);
    acc.w = fmaf(dd2, hv.w, bv.w);
    int r0 = rowptr[gn], r1 = rowptr[gn+1];
    for (int e = r0; e < r1; ++e) {
      int2 p = csr_sw[e];                // uniform across the 4-lane group
      int sl = p.x - gbase;
      float w = (MODE == 2) ? 1.f : __int_as_float(p.y);
      float c = dd * sDW[sl] * w;        // 0 if src or dst dead
      float4 v = sHB4[sl*4 + l4];
      acc.x = fmaf(c, v.x, acc.x);
      acc.y = fmaf(c, v.y, acc.y);
      acc.z = fmaf(c, v.z, acc.z);
      acc.w = fmaf(c, v.w, acc.w);
    }
    acc.x = fmaxf(acc.x, 0.f); acc.y = fmaxf(acc.y, 0.f);
    acc.z = fmaxf(acc.z, 0.f); acc.w = fmaxf(acc.w, 0.f);
    ((float4*)hA)[(size_t)quarter*BNODES*4 + (size_t)gn*4 + l4] = acc;  // quarter-major
    float dot = acc.x*wp.x + acc.y*wp.y + acc.z*wp.z + acc.w*wp.w;
    dot += __shfl_xor(dot, 2, 4);
    dot += __shfl_xor(dot, 1, 4);
    if (l4 == 0) qpart[quarter*BNODES + gn] = dot;
  }
}

// ---------------- q finalize: q = dinvU * (qp0+qp1+qp2+qp3) ----------------
__global__ void k_qfin(const float* __restrict__ dinvU, const float* __restrict__ qp,
                       float* __restrict__ q) {
  int i = blockIdx.x*256 + threadIdx.x;
  if (i < BNODES)
    q[i] = dinvU[i]*(qp[i] + qp[BNODES + i] + qp[2*BNODES + i] + qp[3*BNODES + i]);
}

// ---------------- scoring aggregation (q self-masking; degree-sorted) ----------------
__global__ void k_score(const int* __restrict__ rowptr, const int2* __restrict__ csr_sw,
                        const int* __restrict__ perm,
                        const float* __restrict__ dinvU, const float* __restrict__ q,
                        const float* __restrict__ bp, float* __restrict__ score) {
  int t = threadIdx.x;
  int l16 = t & 15;
  int pos = blockIdx.x*16 + (t >> 4);
  int gb = pos & ~(NN-1);
  int d = gb + perm[pos];
  float du = dinvU[d];
  float sum = 0.f;
  if (du != 0.f) {
    int r0 = rowptr[d], r1 = rowptr[d+1];
    for (int base = r0; base < r1; base += 16)
      if (base + l16 < r1) sum += q[csr_sw[base + l16].x];
  }
  #pragma unroll
  for (int off = 8; off; off >>= 1) sum += __shfl_xor(sum, off, 16);
  if (l16 == 0) score[d] = bp[0] + du*(q[d] + sum);
}

// ---------------- top-k rank: 4 blocks/graph; alive test = dinvU != 0 ----------------
__global__ void k_topk(const float* __restrict__ score,
                       const float* __restrict__ dinvU, int k,
                       float* __restrict__ tm, int* __restrict__ aliveN) {
  __shared__ float sc[NN];
  int b = blockIdx.x >> 2, p = blockIdx.x & 3;
  int t = threadIdx.x;
  int gbase = b*NN;
  #pragma unroll
  for (int i = 0; i < 4; ++i) {
    int n = i*256 + t;
    sc[n] = (dinvU[gbase + n] != 0.f) ? score[gbase + n] : -INFINITY;
  }
  __syncthreads();
  int n = p*256 + t;              // this thread's node
  int node = gbase + n;
  float me = sc[n];
  float raw = score[node];
  int rank = 0;
  const float4* sc4 = (const float4*)sc;
  for (int j4 = 0; j4 < NN/4; ++j4) {
    float4 o = sc4[j4];
    int jb = j4*4;
    rank += (o.x > me) || (o.x == me && jb+0 < n);
    rank += (o.y > me) || (o.y == me && jb+1 < n);
    rank += (o.z > me) || (o.z == me && jb+2 < n);
    rank += (o.w > me) || (o.w == me && jb+3 < n);
  }
  int sel = (rank < k) ? 1 : 0;
  aliveN[node] = sel;
  tm[node] = sel ? tanhf(raw) : 0.f;
}

// ---------------- degrees (next layer): degree-sorted, full grid ----------------
template<int MODE>
__global__ void k_degs(const int* __restrict__ rowptr, const int2* __restrict__ csr_sw,
                       const int* __restrict__ perm, const int* __restrict__ alive,
                       float* __restrict__ dinvW, float* __restrict__ dinvU) {
  int t = threadIdx.x;
  int l16 = t & 15;
  int pos = blockIdx.x*16 + (t >> 4);
  int gb = pos & ~(NN-1);
  int d = gb + perm[pos];
  int r0 = rowptr[d], r1 = rowptr[d+1];
  float sW = 0.f, sU = 0.f;
  for (int base = r0; base < r1; base += 16) {
    if (base + l16 < r1) {
      int2 p = csr_sw[base + l16];
      if (alive[p.x]) { sW += (MODE == 2) ? 1.f : __int_as_float(p.y); sU += 1.f; }
    }
  }
  #pragma unroll
  for (int off = 8; off; off >>= 1) {
    sW += __shfl_xor(sW, off, 16);
    sU += __shfl_xor(sU, off, 16);
  }
  if (l16 == 0) {
    bool dA = (alive[d] != 0);
    dinvW[d] = dA ? rsqrtf(1.f + sW) : 0.f;
    dinvU[d] = dA ? rsqrtf(1.f + sU) : 0.f;
  }
}

// ---------------- fused readout partials (+ optional pool-scale @ W) ----------------
// hA read quarter-major; hB written quarter-major.
template<bool DOLIN>
__global__ void k_srl(const float* __restrict__ hA, const float* __restrict__ tm,
                      const int* __restrict__ aliveN, const float* __restrict__ W,
                      float* __restrict__ hB,
                      float* __restrict__ pmax, float* __restrict__ psum) {
  __shared__ float sX[64][65];
  __shared__ float sW[64*64];
  __shared__ float sTm[64];
  __shared__ int sAl[64];
  __shared__ float rm[4][FH], rs[4][FH];
  int t = threadIdx.x;
  int blk = blockIdx.x;
  int nb = blk*64;
  if (DOLIN)
    for (int i = t; i < 1024; i += 256) ((float4*)sW)[i] = ((const float4*)W)[i];
  if (t < 64) { sTm[t] = tm[nb + t]; sAl[t] = aliveN[nb + t]; }
  __syncthreads();
  // stage sX = tm * hA (quarter-major source)
  #pragma unroll
  for (int q = 0; q < 4; ++q) {
    const float* hq = hA + (size_t)q*BNODES*16 + (size_t)nb*16;
    #pragma unroll
    for (int i = 0; i < 4; ++i) {
      int idx = i*256 + t;          // 1024 floats = 64 nodes x 16
      int n = idx >> 4, ff = idx & 15;
      sX[n][q*16 + ff] = hq[idx] * sTm[n];
    }
  }
  __syncthreads();
  {
    int f = t & 63, r = t >> 6;
    float mx = -INFINITY, sm = 0.f;
    #pragma unroll
    for (int i = 0; i < 16; ++i) {
      int n = r + i*4;
      float v = sX[n][f];
      if (sAl[n]) { mx = fmaxf(mx, v); sm += v; }
    }
    rm[r][f] = mx; rs[r][f] = sm;
  }
  __syncthreads();
  if (t < FH) {
    float m2 = fmaxf(fmaxf(rm[0][t], rm[1][t]), fmaxf(rm[2][t], rm[3][t]));
    float s2 = rs[0][t] + rs[1][t] + rs[2][t] + rs[3][t];
    pmax[blk*FH + t] = m2;
    psum[blk*FH + t] = s2;
  }
  if (DOLIN) {
    int node = t >> 2;
    int quarter = t & 3;
    int f0 = quarter * 16;
    float4 a0 = {0,0,0,0}, a1 = a0, a2 = a0, a3 = a0;
    #pragma unroll 4
    for (int k = 0; k < 64; ++k) {
      float xv = sX[node][k];
      const float4 w0 = *(const float4*)&sW[k*64 + f0];
      const float4 w1 = *(const float4*)&sW[k*64 + f0 + 4];
      const float4 w2 = *(const float4*)&sW[k*64 + f0 + 8];
      const float4 w3 = *(const float4*)&sW[k*64 + f0 + 12];
      a0.x = fmaf(xv, w0.x, a0.x); a0.y = fmaf(xv, w0.y, a0.y);
      a0.z = fmaf(xv, w0.z, a0.z); a0.w = fmaf(xv, w0.w, a0.w);
      a1.x = fmaf(xv, w1.x, a1.x); a1.y = fmaf(xv, w1.y, a1.y);
      a1.z = fmaf(xv, w1.z, a1.z); a1.w = fmaf(xv, w1.w, a1.w);
      a2.x = fmaf(xv, w2.x, a2.x); a2.y = fmaf(xv, w2.y, a2.y);
      a2.z = fmaf(xv, w2.z, a2.z); a2.w = fmaf(xv, w2.w, a2.w);
      a3.x = fmaf(xv, w3.x, a3.x); a3.y = fmaf(xv, w3.y, a3.y);
      a3.z = fmaf(xv, w3.z, a3.z); a3.w = fmaf(xv, w3.w, a3.w);
    }
    // quarter-major hB write: [quarter][node][16]
    float4* dst = (float4*)(hB + (size_t)quarter*BNODES*16 + (size_t)(nb + node)*16);
    dst[0] = a0; dst[1] = a1; dst[2] = a2; dst[3] = a3;
  }
}

// ---------------- partial reduce + MLP head + log_softmax ----------------
__global__ void k_mlp(const float* __restrict__ pmax, const float* __restrict__ psum,
                      const float* __restrict__ Wl1, const float* __restrict__ bl1,
                      const float* __restrict__ Wl2, const float* __restrict__ bl2,
                      const float* __restrict__ Wl3, const float* __restrict__ bl3,
                      float* __restrict__ out) {
  __shared__ float sg[2*FH];
  __shared__ float l1[FH];
  __shared__ float l2[FH/2];
  __shared__ float l3[2];
  int b = blockIdx.x, t = threadIdx.x;
  const float kf[3] = {(float)KK1, (float)KK2, (float)KK3};
  float gm = 0.f, gs = 0.f;
  #pragma unroll
  for (int l = 0; l < 3; ++l) {
    const float* pm = pmax + (size_t)l*NB*16*FH + (b*16)*FH;
    const float* ps = psum + (size_t)l*NB*16*FH + (b*16)*FH;
    float mm = -INFINITY, ss = 0.f;
    #pragma unroll
    for (int p = 0; p < 16; ++p) {
      mm = fmaxf(mm, pm[p*FH + t]);
      ss += ps[p*FH + t];
    }
    gm += mm;
    gs += ss / kf[l];
  }
  sg[t] = gm;
  sg[FH + t] = gs;
  __syncthreads();
  float acc = bl1[t];
  #pragma unroll
  for (int k = 0; k < 2*FH; ++k) acc = fmaf(sg[k], Wl1[k*FH + t], acc);
  l1[t] = fmaxf(acc, 0.f);
  __syncthreads();
  if (t < 32) {
    float a2 = bl2[t];
    #pragma unroll
    for (int k = 0; k < FH; ++k) a2 = fmaf(l1[k], Wl2[k*32 + t], a2);
    l2[t] = fmaxf(a2, 0.f);
  }
  __syncthreads();
  if (t < 2) {
    float a3 = bl3[t];
    #pragma unroll
    for (int k = 0; k < 32; ++k) a3 = fmaf(l2[k], Wl3[k*2 + t], a3);
    l3[t] = a3;
  }
  __syncthreads();
  if (t == 0) {
    float m = fmaxf(l3[0], l3[1]);
    float lse = m + logf(expf(l3[0]-m) + expf(l3[1]-m));
    out[b*2+0] = l3[0] - lse;
    out[b*2+1] = l3[1] - lse;
  }
}

extern "C" void kernel_launch(void* const* d_in, const int* in_sizes, int n_in,
                              void* d_out, int out_size, void* d_ws, size_t ws_size,
                              hipStream_t stream) {
  const float* x   = (const float*)d_in[0];
  const float* ea  = (const float*)d_in[1];
  const float* W1  = (const float*)d_in[2];
  const float* b1  = (const float*)d_in[3];
  const float* Wp1 = (const float*)d_in[4];
  const float* bp1 = (const float*)d_in[5];
  const float* W2  = (const float*)d_in[6];
  const float* b2  = (const float*)d_in[7];
  const float* Wp2 = (const float*)d_in[8];
  const float* bp2 = (const float*)d_in[9];
  const float* W3  = (const float*)d_in[10];
  const float* b3  = (const float*)d_in[11];
  const float* Wp3 = (const float*)d_in[12];
  const float* bp3 = (const float*)d_in[13];
  const float* Wl1 = (const float*)d_in[14];
  const float* bl1 = (const float*)d_in[15];
  const float* Wl2 = (const float*)d_in[16];
  const float* bl2 = (const float*)d_in[17];
  const float* Wl3 = (const float*)d_in[18];
  const float* bl3 = (const float*)d_in[19];
  const int*   ei  = (const int*)d_in[20];
  float* out = (float*)d_out;

  int2* csr_sw = (int2*)d_ws;                        // NE
  float* hA    = (float*)(csr_sw + NE);              // BNODES*FH (quarter-major)
  float* hB    = hA + (size_t)BNODES*FH;             // BNODES*FH (quarter-major)
  float* dinvW = hB + (size_t)BNODES*FH;             // BNODES
  float* dinvU = dinvW + BNODES;                     // BNODES
  float* qpart = dinvU + BNODES;                     // 4*BNODES
  float* q     = qpart + 4*BNODES;                   // BNODES
  float* score = q + BNODES;                         // BNODES
  float* tm    = score + BNODES;                     // BNODES
  float* pmax  = tm + BNODES;                        // 3*NB*16*FH
  float* psum  = pmax + 3*NB*16*FH;                  // 3*NB*16*FH
  int* aliveN  = (int*)(psum + 3*NB*16*FH);          // BNODES
  int* rowptr  = aliveN + BNODES;                    // BNODES+1
  int* perm    = rowptr + BNODES + 2;                // BNODES

  const size_t gathLds = (size_t)NN*16*sizeof(float);   // 64 KB
  const int gS = BNODES/64;                             // 2048 srl blocks
  const int gG = BNODES/16;                             // 8192 score/degs blocks
  const int gN = BNODES/256;                            // 512

  k_csr<<<NB, 1024, EPG*sizeof(int2), stream>>>(ei, ea, rowptr, csr_sw, dinvW, dinvU, perm);

  // ===== Layer 1 =====
  k_gath<0,true><<<NB*4, 1024, gathLds, stream>>>(rowptr, csr_sw, perm, dinvW, x, W1, b1, Wp1, hA, qpart);
  k_qfin<<<gN, 256, 0, stream>>>(dinvU, qpart, q);
  k_score<<<gG, 256, 0, stream>>>(rowptr, csr_sw, perm, dinvU, q, bp1, score);
  k_topk<<<NB*4, 256, 0, stream>>>(score, dinvU, KK1, tm, aliveN);
  k_srl<true><<<gS, 256, 0, stream>>>(hA, tm, aliveN, W2, hB, pmax, psum);
  k_degs<1><<<gG, 256, 0, stream>>>(rowptr, csr_sw, perm, aliveN, dinvW, dinvU);

  // ===== Layer 2 =====
  k_gath<1,false><<<NB*4, 1024, gathLds, stream>>>(rowptr, csr_sw, perm, dinvW, hB, W1, b2, Wp2, hA, qpart);
  k_qfin<<<gN, 256, 0, stream>>>(dinvU, qpart, q);
  k_score<<<gG, 256, 0, stream>>>(rowptr, csr_sw, perm, dinvU, q, bp2, score);
  k_topk<<<NB*4, 256, 0, stream>>>(score, dinvU, KK2, tm, aliveN);
  k_srl<true><<<gS, 256, 0, stream>>>(hA, tm, aliveN, W3, hB, pmax + NB*16*FH, psum + NB*16*FH);
  k_degs<2><<<gG, 256, 0, stream>>>(rowptr, csr_sw, perm, aliveN, dinvW, dinvU);

  // ===== Layer 3 =====
  k_gath<2,false><<<NB*4, 1024, gathLds, stream>>>(rowptr, csr_sw, perm, dinvW, hB, W1, b3, Wp3, hA, qpart);
  k_qfin<<<gN, 256, 0, stream>>>(dinvU, qpart, q);
  k_score<<<gG, 256, 0, stream>>>(rowptr, csr_sw, perm, dinvU, q, bp3, score);
  k_topk<<<NB*4, 256, 0, stream>>>(score, dinvU, KK3, tm, aliveN);
  k_srl<false><<<gS, 256, 0, stream>>>(hA, tm, aliveN, W3, hB, pmax + 2*NB*16*FH, psum + 2*NB*16*FH);

  k_mlp<<<NB, FH, 0, stream>>>(pmax, psum, Wl1, bl1, Wl2, bl2, Wl3, bl3, out);
}

// Round 23
// 367.190 us; speedup vs baseline: 1.0684x; 1.0573x over previous
//
#include <hip/hip_runtime.h>
#include <math.h>

#define NB 128            // graphs
#define NN 1024           // nodes per graph
#define BNODES (NB*NN)    // 131072
#define NE 2097152        // edges
#define EPG (NE/NB)       // 16384 edges per graph (edge list is graph-blocked)
#define EPT (EPG/NN)      // 16 edges per thread in k_csr
#define FH 64             // hidden
#define KK1 820
#define KK2 656
#define KK3 525

// ---------------- one-kernel CSR build + layer-1 degrees ----------------
__global__ __launch_bounds__(1024) void k_csr(const int* __restrict__ ei,
                                              const float* __restrict__ ea,
                                              int* __restrict__ rowptr,
                                              int2* __restrict__ csr_sw,
                                              float* __restrict__ dinvW,
                                              float* __restrict__ dinvU) {
  extern __shared__ int2 lcsr[];          // EPG entries = 128 KB
  __shared__ int cnt[NN];
  __shared__ int cur[NN];
  __shared__ float wsum[NN];
  int b = blockIdx.x, t = threadIdx.x;
  int node = b*NN + t;
  cnt[t] = 0;
  wsum[t] = 0.f;
  __syncthreads();
  int ebase = b*EPG;
  int se[EPT]; int de[EPT]; float we[EPT];
  #pragma unroll
  for (int i = 0; i < EPT; ++i) {
    int e = ebase + i*NN + t;
    se[i] = ei[e];
    de[i] = ei[NE + e] - b*NN;
    we[i] = ea[e];
    atomicAdd(&cnt[de[i]], 1);
    atomicAdd(&wsum[de[i]], we[i]);
  }
  __syncthreads();
  int v = cnt[t];
  for (int off = 1; off < NN; off <<= 1) {
    int u = (t >= off) ? cnt[t - off] : 0;
    __syncthreads();
    cnt[t] += u;
    __syncthreads();
  }
  int excl = cnt[t] - v;
  rowptr[node] = ebase + excl;
  cur[t] = excl;
  dinvW[node] = rsqrtf(1.f + wsum[t]);    // layer-1 weighted degree (all alive)
  dinvU[node] = rsqrtf(1.f + (float)v);   // layer-1 unweighted degree
  if (b == NB-1 && t == NN-1) rowptr[BNODES] = NE;
  __syncthreads();
  #pragma unroll
  for (int i = 0; i < EPT; ++i) {
    int pos = atomicAdd(&cur[de[i]], 1);
    lcsr[pos] = make_int2(se[i], __float_as_int(we[i]));
  }
  __syncthreads();
  float4* dst4 = (float4*)(csr_sw + ebase);
  const float4* src4 = (const float4*)lcsr;
  #pragma unroll
  for (int i = 0; i < EPG/2/NN; ++i)
    dst4[i*NN + t] = src4[i*NN + t];
}

// ---------------- LDS-staged GCN gather: 1 block per (graph, feature-QUARTER) ----------------
// blockIdx = quarter*NB + b -> all 4 slices of graph b co-located per XCD.
template<int MODE, bool L1S>
__global__ __launch_bounds__(1024, 8) void k_gath(
    const int* __restrict__ rowptr, const int2* __restrict__ csr_sw,
    const float* __restrict__ dinvW, const float* __restrict__ src,  // hBq or x
    const float* __restrict__ Wl,                                    // W1 (L1S only)
    const float* __restrict__ bias, const float* __restrict__ Wp,
    float* __restrict__ hA, float* __restrict__ qpart) {
  extern __shared__ float sHB[];        // [NN][16] = 64 KB
  __shared__ float sDW[NN];
  __shared__ float sWp[16];
  __shared__ float sB[16];
  __shared__ float sW1[32];
  int b = blockIdx.x & (NB-1), quarter = blockIdx.x >> 7;
  int t = threadIdx.x, l4 = t & 3;
  int gbase = b*NN;
  sDW[t] = dinvW[gbase + t];
  if (t < 16) { sWp[t] = Wp[quarter*16 + t]; sB[t] = bias[quarter*16 + t]; }
  float4* sHB4 = (float4*)sHB;
  if (L1S) {
    if (t < 16) { sW1[t] = Wl[quarter*16 + t]; sW1[16 + t] = Wl[64 + quarter*16 + t]; }
    __syncthreads();
    #pragma unroll
    for (int i = 0; i < 16; ++i) {
      int el = i*1024 + t;               // 16384 floats
      int n = el >> 4, ff = el & 15;
      float x0 = src[(size_t)(gbase + n)*2];
      float x1 = src[(size_t)(gbase + n)*2 + 1];
      sHB[n*16 + ff] = x0*sW1[ff] + x1*sW1[16 + ff];
    }
  } else {
    const float4* hq4 = (const float4*)src + (size_t)quarter*BNODES*4 + (size_t)gbase*4;
    #pragma unroll
    for (int i = 0; i < 4; ++i) {
      int idx = i*1024 + t;              // 4096 float4 = 64 KB
      sHB4[idx] = hq4[idx];
    }
  }
  __syncthreads();
  float4 bv = ((const float4*)sB)[l4];
  float4 wp = ((const float4*)sWp)[l4];
  #pragma unroll 1
  for (int pass = 0; pass < 4; ++pass) {
    int n = pass*256 + (t >> 2);
    int gn = gbase + n;
    float dd = sDW[n];
    float4 hv = sHB4[n*4 + l4];
    float dd2 = dd*dd;
    float4 acc;
    acc.x = fmaf(dd2, hv.x, bv.x);
    acc.y = fmaf(dd2, hv.y, bv.y);
    acc.z = fmaf(dd2, hv.z, bv.z);
    acc.w = fmaf(dd2, hv.w, bv.w);
    int r0 = rowptr[gn], r1 = rowptr[gn+1];
    for (int e = r0; e < r1; ++e) {
      int2 p = csr_sw[e];                // uniform across the 4-lane group
      int sl = p.x - gbase;
      float w = (MODE == 2) ? 1.f : __int_as_float(p.y);
      float c = dd * sDW[sl] * w;        // 0 if src or dst dead
      float4 v = sHB4[sl*4 + l4];
      acc.x = fmaf(c, v.x, acc.x);
      acc.y = fmaf(c, v.y, acc.y);
      acc.z = fmaf(c, v.z, acc.z);
      acc.w = fmaf(c, v.w, acc.w);
    }
    acc.x = fmaxf(acc.x, 0.f); acc.y = fmaxf(acc.y, 0.f);
    acc.z = fmaxf(acc.z, 0.f); acc.w = fmaxf(acc.w, 0.f);
    ((float4*)hA)[(size_t)quarter*BNODES*4 + (size_t)gn*4 + l4] = acc;  // quarter-major
    float dot = acc.x*wp.x + acc.y*wp.y + acc.z*wp.z + acc.w*wp.w;
    dot += __shfl_xor(dot, 2, 4);
    dot += __shfl_xor(dot, 1, 4);
    if (l4 == 0) qpart[quarter*BNODES + gn] = dot;
  }
}

// ---------------- q finalize: q = dinvU * (qp0+qp1+qp2+qp3) ----------------
__global__ void k_qfin(const float* __restrict__ dinvU, const float* __restrict__ qp,
                       float* __restrict__ q) {
  int i = blockIdx.x*256 + threadIdx.x;
  if (i < BNODES)
    q[i] = dinvU[i]*(qp[i] + qp[BNODES + i] + qp[2*BNODES + i] + qp[3*BNODES + i]);
}

// ---------------- scoring aggregation (q self-masking, full grid) ----------------
__global__ void k_score(const int* __restrict__ rowptr, const int2* __restrict__ csr_sw,
                        const float* __restrict__ dinvU, const float* __restrict__ q,
                        const float* __restrict__ bp, float* __restrict__ score) {
  int t = threadIdx.x;
  int l16 = t & 15;
  int d = blockIdx.x*16 + (t >> 4);
  float du = dinvU[d];
  float sum = 0.f;
  if (du != 0.f) {
    int r0 = rowptr[d], r1 = rowptr[d+1];
    for (int base = r0; base < r1; base += 16)
      if (base + l16 < r1) sum += q[csr_sw[base + l16].x];
  }
  #pragma unroll
  for (int off = 8; off; off >>= 1) sum += __shfl_xor(sum, off, 16);
  if (l16 == 0) score[d] = bp[0] + du*(q[d] + sum);
}

// ---------------- top-k rank: 4 blocks/graph; alive test = dinvU != 0 ----------------
__global__ void k_topk(const float* __restrict__ score,
                       const float* __restrict__ dinvU, int k,
                       float* __restrict__ tm, int* __restrict__ aliveN) {
  __shared__ float sc[NN];
  int b = blockIdx.x >> 2, p = blockIdx.x & 3;
  int t = threadIdx.x;
  int gbase = b*NN;
  #pragma unroll
  for (int i = 0; i < 4; ++i) {
    int n = i*256 + t;
    sc[n] = (dinvU[gbase + n] != 0.f) ? score[gbase + n] : -INFINITY;
  }
  __syncthreads();
  int n = p*256 + t;              // this thread's node
  int node = gbase + n;
  float me = sc[n];
  float raw = score[node];
  int rank = 0;
  const float4* sc4 = (const float4*)sc;
  for (int j4 = 0; j4 < NN/4; ++j4) {
    float4 o = sc4[j4];
    int jb = j4*4;
    rank += (o.x > me) || (o.x == me && jb+0 < n);
    rank += (o.y > me) || (o.y == me && jb+1 < n);
    rank += (o.z > me) || (o.z == me && jb+2 < n);
    rank += (o.w > me) || (o.w == me && jb+3 < n);
  }
  int sel = (rank < k) ? 1 : 0;
  aliveN[node] = sel;
  tm[node] = sel ? tanhf(raw) : 0.f;
}

// ---------------- fused readout partials + pool-scale GEMM + NEXT-layer degrees ----------------
// hA read quarter-major; hB written quarter-major. DEGMODE: 0 none, 1 ea*mask, 2 mask.
// The degs edge-walk (latency-bound) overlaps with the GEMM (VALU-bound).
template<bool DOLIN, int DEGMODE>
__global__ void k_srl(const float* __restrict__ hA, const float* __restrict__ tm,
                      const int* __restrict__ aliveN, const float* __restrict__ W,
                      float* __restrict__ hB,
                      float* __restrict__ pmax, float* __restrict__ psum,
                      const int* __restrict__ rowptr, const int2* __restrict__ csr_sw,
                      float* __restrict__ dinvW, float* __restrict__ dinvU) {
  __shared__ float sX[64][65];
  __shared__ float sW[64*64];
  __shared__ float sTm[64];
  __shared__ int sAl[64];
  __shared__ float rm[4][FH], rs[4][FH];
  int t = threadIdx.x;
  int blk = blockIdx.x;
  int nb = blk*64;
  if (DOLIN)
    for (int i = t; i < 1024; i += 256) ((float4*)sW)[i] = ((const float4*)W)[i];
  if (t < 64) { sTm[t] = tm[nb + t]; sAl[t] = aliveN[nb + t]; }
  __syncthreads();
  // stage sX = tm * hA (quarter-major source)
  #pragma unroll
  for (int q = 0; q < 4; ++q) {
    const float* hq = hA + (size_t)q*BNODES*16 + (size_t)nb*16;
    #pragma unroll
    for (int i = 0; i < 4; ++i) {
      int idx = i*256 + t;          // 1024 floats = 64 nodes x 16
      int n = idx >> 4, ff = idx & 15;
      sX[n][q*16 + ff] = hq[idx] * sTm[n];
    }
  }
  __syncthreads();
  {
    int f = t & 63, r = t >> 6;
    float mx = -INFINITY, sm = 0.f;
    #pragma unroll
    for (int i = 0; i < 16; ++i) {
      int n = r + i*4;
      float v = sX[n][f];
      if (sAl[n]) { mx = fmaxf(mx, v); sm += v; }
    }
    rm[r][f] = mx; rs[r][f] = sm;
  }
  __syncthreads();
  if (t < FH) {
    float m2 = fmaxf(fmaxf(rm[0][t], rm[1][t]), fmaxf(rm[2][t], rm[3][t]));
    float s2 = rs[0][t] + rs[1][t] + rs[2][t] + rs[3][t];
    pmax[blk*FH + t] = m2;
    psum[blk*FH + t] = s2;
  }
  // ---- next-layer degrees for this tile's 64 nodes (overlaps with GEMM below) ----
  if (DEGMODE != 0) {
    int g = t >> 4, l16 = t & 15;       // 16 groups x 16 lanes
    for (int i = 0; i < 4; ++i) {
      int n = g*4 + i;                  // local node 0..63
      int d = nb + n;
      int r0 = rowptr[d], r1 = rowptr[d+1];
      float sWd = 0.f, sU = 0.f;
      for (int base = r0; base < r1; base += 16) {
        if (base + l16 < r1) {
          int2 p = csr_sw[base + l16];
          if (aliveN[p.x]) { sWd += (DEGMODE == 2) ? 1.f : __int_as_float(p.y); sU += 1.f; }
        }
      }
      #pragma unroll
      for (int off = 8; off; off >>= 1) {
        sWd += __shfl_xor(sWd, off, 16);
        sU  += __shfl_xor(sU, off, 16);
      }
      if (l16 == 0) {
        bool dA = (sAl[n] != 0);
        dinvW[d] = dA ? rsqrtf(1.f + sWd) : 0.f;
        dinvU[d] = dA ? rsqrtf(1.f + sU) : 0.f;
      }
    }
  }
  if (DOLIN) {
    int node = t >> 2;
    int quarter = t & 3;
    int f0 = quarter * 16;
    float4 a0 = {0,0,0,0}, a1 = a0, a2 = a0, a3 = a0;
    #pragma unroll 4
    for (int k = 0; k < 64; ++k) {
      float xv = sX[node][k];
      const float4 w0 = *(const float4*)&sW[k*64 + f0];
      const float4 w1 = *(const float4*)&sW[k*64 + f0 + 4];
      const float4 w2 = *(const float4*)&sW[k*64 + f0 + 8];
      const float4 w3 = *(const float4*)&sW[k*64 + f0 + 12];
      a0.x = fmaf(xv, w0.x, a0.x); a0.y = fmaf(xv, w0.y, a0.y);
      a0.z = fmaf(xv, w0.z, a0.z); a0.w = fmaf(xv, w0.w, a0.w);
      a1.x = fmaf(xv, w1.x, a1.x); a1.y = fmaf(xv, w1.y, a1.y);
      a1.z = fmaf(xv, w1.z, a1.z); a1.w = fmaf(xv, w1.w, a1.w);
      a2.x = fmaf(xv, w2.x, a2.x); a2.y = fmaf(xv, w2.y, a2.y);
      a2.z = fmaf(xv, w2.z, a2.z); a2.w = fmaf(xv, w2.w, a2.w);
      a3.x = fmaf(xv, w3.x, a3.x); a3.y = fmaf(xv, w3.y, a3.y);
      a3.z = fmaf(xv, w3.z, a3.z); a3.w = fmaf(xv, w3.w, a3.w);
    }
    // quarter-major hB write: [quarter][node][16]
    float4* dst = (float4*)(hB + (size_t)quarter*BNODES*16 + (size_t)(nb + node)*16);
    dst[0] = a0; dst[1] = a1; dst[2] = a2; dst[3] = a3;
  }
}

// ---------------- partial reduce + MLP head + log_softmax ----------------
__global__ void k_mlp(const float* __restrict__ pmax, const float* __restrict__ psum,
                      const float* __restrict__ Wl1, const float* __restrict__ bl1,
                      const float* __restrict__ Wl2, const float* __restrict__ bl2,
                      const float* __restrict__ Wl3, const float* __restrict__ bl3,
                      float* __restrict__ out) {
  __shared__ float sg[2*FH];
  __shared__ float l1[FH];
  __shared__ float l2[FH/2];
  __shared__ float l3[2];
  int b = blockIdx.x, t = threadIdx.x;
  const float kf[3] = {(float)KK1, (float)KK2, (float)KK3};
  float gm = 0.f, gs = 0.f;
  #pragma unroll
  for (int l = 0; l < 3; ++l) {
    const float* pm = pmax + (size_t)l*NB*16*FH + (b*16)*FH;
    const float* ps = psum + (size_t)l*NB*16*FH + (b*16)*FH;
    float mm = -INFINITY, ss = 0.f;
    #pragma unroll
    for (int p = 0; p < 16; ++p) {
      mm = fmaxf(mm, pm[p*FH + t]);
      ss += ps[p*FH + t];
    }
    gm += mm;
    gs += ss / kf[l];
  }
  sg[t] = gm;
  sg[FH + t] = gs;
  __syncthreads();
  float acc = bl1[t];
  #pragma unroll
  for (int k = 0; k < 2*FH; ++k) acc = fmaf(sg[k], Wl1[k*FH + t], acc);
  l1[t] = fmaxf(acc, 0.f);
  __syncthreads();
  if (t < 32) {
    float a2 = bl2[t];
    #pragma unroll
    for (int k = 0; k < FH; ++k) a2 = fmaf(l1[k], Wl2[k*32 + t], a2);
    l2[t] = fmaxf(a2, 0.f);
  }
  __syncthreads();
  if (t < 2) {
    float a3 = bl3[t];
    #pragma unroll
    for (int k = 0; k < 32; ++k) a3 = fmaf(l2[k], Wl3[k*2 + t], a3);
    l3[t] = a3;
  }
  __syncthreads();
  if (t == 0) {
    float m = fmaxf(l3[0], l3[1]);
    float lse = m + logf(expf(l3[0]-m) + expf(l3[1]-m));
    out[b*2+0] = l3[0] - lse;
    out[b*2+1] = l3[1] - lse;
  }
}

extern "C" void kernel_launch(void* const* d_in, const int* in_sizes, int n_in,
                              void* d_out, int out_size, void* d_ws, size_t ws_size,
                              hipStream_t stream) {
  const float* x   = (const float*)d_in[0];
  const float* ea  = (const float*)d_in[1];
  const float* W1  = (const float*)d_in[2];
  const float* b1  = (const float*)d_in[3];
  const float* Wp1 = (const float*)d_in[4];
  const float* bp1 = (const float*)d_in[5];
  const float* W2  = (const float*)d_in[6];
  const float* b2  = (const float*)d_in[7];
  const float* Wp2 = (const float*)d_in[8];
  const float* bp2 = (const float*)d_in[9];
  const float* W3  = (const float*)d_in[10];
  const float* b3  = (const float*)d_in[11];
  const float* Wp3 = (const float*)d_in[12];
  const float* bp3 = (const float*)d_in[13];
  const float* Wl1 = (const float*)d_in[14];
  const float* bl1 = (const float*)d_in[15];
  const float* Wl2 = (const float*)d_in[16];
  const float* bl2 = (const float*)d_in[17];
  const float* Wl3 = (const float*)d_in[18];
  const float* bl3 = (const float*)d_in[19];
  const int*   ei  = (const int*)d_in[20];
  float* out = (float*)d_out;

  int2* csr_sw = (int2*)d_ws;                        // NE
  float* hA    = (float*)(csr_sw + NE);              // BNODES*FH (quarter-major)
  float* hB    = hA + (size_t)BNODES*FH;             // BNODES*FH (quarter-major)
  float* dinvW = hB + (size_t)BNODES*FH;             // BNODES
  float* dinvU = dinvW + BNODES;                     // BNODES
  float* qpart = dinvU + BNODES;                     // 4*BNODES
  float* q     = qpart + 4*BNODES;                   // BNODES
  float* score = q + BNODES;                         // BNODES
  float* tm    = score + BNODES;                     // BNODES
  float* pmax  = tm + BNODES;                        // 3*NB*16*FH
  float* psum  = pmax + 3*NB*16*FH;                  // 3*NB*16*FH
  int* aliveN  = (int*)(psum + 3*NB*16*FH);          // BNODES
  int* rowptr  = aliveN + BNODES;                    // BNODES+1

  const size_t gathLds = (size_t)NN*16*sizeof(float);   // 64 KB
  const int gS = BNODES/64;                             // 2048 srl blocks
  const int gG = BNODES/16;                             // 8192 score blocks
  const int gN = BNODES/256;                            // 512

  k_csr<<<NB, 1024, EPG*sizeof(int2), stream>>>(ei, ea, rowptr, csr_sw, dinvW, dinvU);

  // ===== Layer 1 =====
  k_gath<0,true><<<NB*4, 1024, gathLds, stream>>>(rowptr, csr_sw, dinvW, x, W1, b1, Wp1, hA, qpart);
  k_qfin<<<gN, 256, 0, stream>>>(dinvU, qpart, q);
  k_score<<<gG, 256, 0, stream>>>(rowptr, csr_sw, dinvU, q, bp1, score);
  k_topk<<<NB*4, 256, 0, stream>>>(score, dinvU, KK1, tm, aliveN);
  k_srl<true,1><<<gS, 256, 0, stream>>>(hA, tm, aliveN, W2, hB, pmax, psum,
                                        rowptr, csr_sw, dinvW, dinvU);

  // ===== Layer 2 =====
  k_gath<1,false><<<NB*4, 1024, gathLds, stream>>>(rowptr, csr_sw, dinvW, hB, W1, b2, Wp2, hA, qpart);
  k_qfin<<<gN, 256, 0, stream>>>(dinvU, qpart, q);
  k_score<<<gG, 256, 0, stream>>>(rowptr, csr_sw, dinvU, q, bp2, score);
  k_topk<<<NB*4, 256, 0, stream>>>(score, dinvU, KK2, tm, aliveN);
  k_srl<true,2><<<gS, 256, 0, stream>>>(hA, tm, aliveN, W3, hB, pmax + NB*16*FH, psum + NB*16*FH,
                                        rowptr, csr_sw, dinvW, dinvU);

  // ===== Layer 3 =====
  k_gath<2,false><<<NB*4, 1024, gathLds, stream>>>(rowptr, csr_sw, dinvW, hB, W1, b3, Wp3, hA, qpart);
  k_qfin<<<gN, 256, 0, stream>>>(dinvU, qpart, q);
  k_score<<<gG, 256, 0, stream>>>(rowptr, csr_sw, dinvU, q, bp3, score);
  k_topk<<<NB*4, 256, 0, stream>>>(score, dinvU, KK3, tm, aliveN);
  k_srl<false,0><<<gS, 256, 0, stream>>>(hA, tm, aliveN, W3, hB, pmax + 2*NB*16*FH, psum + 2*NB*16*FH,
                                         rowptr, csr_sw, dinvW, dinvU);

  k_mlp<<<NB, FH, 0, stream>>>(pmax, psum, Wl1, bl1, Wl2, bl2, Wl3, bl3, out);
}

// Round 26
// 363.282 us; speedup vs baseline: 1.0799x; 1.0108x over previous
//
#include <hip/hip_runtime.h>
#include <math.h>

#define NB 128            // graphs
#define NN 1024           // nodes per graph
#define BNODES (NB*NN)    // 131072
#define NE 2097152        // edges
#define EPG (NE/NB)       // 16384 edges per graph (edge list is graph-blocked)
#define EPT (EPG/NN)      // 16 edges per thread in k_csr
#define FH 64             // hidden
#define KK1 820
#define KK2 656
#define KK3 525

// ---------------- one-kernel CSR build + layer-1 degrees ----------------
__global__ __launch_bounds__(1024) void k_csr(const int* __restrict__ ei,
                                              const float* __restrict__ ea,
                                              int* __restrict__ rowptr,
                                              int2* __restrict__ csr_sw,
                                              float* __restrict__ dinvW,
                                              float* __restrict__ dinvU) {
  extern __shared__ int2 lcsr[];          // EPG entries = 128 KB
  __shared__ int cnt[NN];
  __shared__ int cur[NN];
  __shared__ float wsum[NN];
  int b = blockIdx.x, t = threadIdx.x;
  int node = b*NN + t;
  cnt[t] = 0;
  wsum[t] = 0.f;
  __syncthreads();
  int ebase = b*EPG;
  int se[EPT]; int de[EPT]; float we[EPT];
  #pragma unroll
  for (int i = 0; i < EPT; ++i) {
    int e = ebase + i*NN + t;
    se[i] = ei[e];
    de[i] = ei[NE + e] - b*NN;
    we[i] = ea[e];
    atomicAdd(&cnt[de[i]], 1);
    atomicAdd(&wsum[de[i]], we[i]);
  }
  __syncthreads();
  int v = cnt[t];
  for (int off = 1; off < NN; off <<= 1) {
    int u = (t >= off) ? cnt[t - off] : 0;
    __syncthreads();
    cnt[t] += u;
    __syncthreads();
  }
  int excl = cnt[t] - v;
  rowptr[node] = ebase + excl;
  cur[t] = excl;
  dinvW[node] = rsqrtf(1.f + wsum[t]);    // layer-1 weighted degree (all alive)
  dinvU[node] = rsqrtf(1.f + (float)v);   // layer-1 unweighted degree
  if (b == NB-1 && t == NN-1) rowptr[BNODES] = NE;
  __syncthreads();
  #pragma unroll
  for (int i = 0; i < EPT; ++i) {
    int pos = atomicAdd(&cur[de[i]], 1);
    lcsr[pos] = make_int2(se[i], __float_as_int(we[i]));
  }
  __syncthreads();
  float4* dst4 = (float4*)(csr_sw + ebase);
  const float4* src4 = (const float4*)lcsr;
  #pragma unroll
  for (int i = 0; i < EPG/2/NN; ++i)
    dst4[i*NN + t] = src4[i*NN + t];
}

// ---------------- LDS-staged GCN gather: 1 block per (graph, feature-QUARTER) ----------------
// blockIdx = quarter*NB + b -> all 4 slices of graph b co-located per XCD.
template<int MODE, bool L1S>
__global__ __launch_bounds__(1024, 8) void k_gath(
    const int* __restrict__ rowptr, const int2* __restrict__ csr_sw,
    const float* __restrict__ dinvW, const float* __restrict__ src,  // hBq or x
    const float* __restrict__ Wl,                                    // W1 (L1S only)
    const float* __restrict__ bias, const float* __restrict__ Wp,
    float* __restrict__ hA, float* __restrict__ qpart) {
  extern __shared__ float sHB[];        // [NN][16] = 64 KB
  __shared__ float sDW[NN];
  __shared__ float sWp[16];
  __shared__ float sB[16];
  __shared__ float sW1[32];
  int b = blockIdx.x & (NB-1), quarter = blockIdx.x >> 7;
  int t = threadIdx.x, l4 = t & 3;
  int gbase = b*NN;
  sDW[t] = dinvW[gbase + t];
  if (t < 16) { sWp[t] = Wp[quarter*16 + t]; sB[t] = bias[quarter*16 + t]; }
  float4* sHB4 = (float4*)sHB;
  if (L1S) {
    if (t < 16) { sW1[t] = Wl[quarter*16 + t]; sW1[16 + t] = Wl[64 + quarter*16 + t]; }
    __syncthreads();
    #pragma unroll
    for (int i = 0; i < 16; ++i) {
      int el = i*1024 + t;               // 16384 floats
      int n = el >> 4, ff = el & 15;
      float x0 = src[(size_t)(gbase + n)*2];
      float x1 = src[(size_t)(gbase + n)*2 + 1];
      sHB[n*16 + ff] = x0*sW1[ff] + x1*sW1[16 + ff];
    }
  } else {
    const float4* hq4 = (const float4*)src + (size_t)quarter*BNODES*4 + (size_t)gbase*4;
    #pragma unroll
    for (int i = 0; i < 4; ++i) {
      int idx = i*1024 + t;              // 4096 float4 = 64 KB
      sHB4[idx] = hq4[idx];
    }
  }
  __syncthreads();
  float4 bv = ((const float4*)sB)[l4];
  float4 wp = ((const float4*)sWp)[l4];
  #pragma unroll 1
  for (int pass = 0; pass < 4; ++pass) {
    int n = pass*256 + (t >> 2);
    int gn = gbase + n;
    float dd = sDW[n];
    float4 hv = sHB4[n*4 + l4];
    float dd2 = dd*dd;
    float4 acc;
    acc.x = fmaf(dd2, hv.x, bv.x);
    acc.y = fmaf(dd2, hv.y, bv.y);
    acc.z = fmaf(dd2, hv.z, bv.z);
    acc.w = fmaf(dd2, hv.w, bv.w);
    int r0 = rowptr[gn], r1 = rowptr[gn+1];
    for (int e = r0; e < r1; ++e) {
      int2 p = csr_sw[e];                // uniform across the 4-lane group
      int sl = p.x - gbase;
      float w = (MODE == 2) ? 1.f : __int_as_float(p.y);
      float c = dd * sDW[sl] * w;        // 0 if src or dst dead
      float4 v = sHB4[sl*4 + l4];
      acc.x = fmaf(c, v.x, acc.x);
      acc.y = fmaf(c, v.y, acc.y);
      acc.z = fmaf(c, v.z, acc.z);
      acc.w = fmaf(c, v.w, acc.w);
    }
    acc.x = fmaxf(acc.x, 0.f); acc.y = fmaxf(acc.y, 0.f);
    acc.z = fmaxf(acc.z, 0.f); acc.w = fmaxf(acc.w, 0.f);
    ((float4*)hA)[(size_t)quarter*BNODES*4 + (size_t)gn*4 + l4] = acc;  // quarter-major
    float dot = acc.x*wp.x + acc.y*wp.y + acc.z*wp.z + acc.w*wp.w;
    dot += __shfl_xor(dot, 2, 4);
    dot += __shfl_xor(dot, 1, 4);
    if (l4 == 0) qpart[quarter*BNODES + gn] = dot;
  }
}

// ---------------- q finalize: q = dinvU * (qp0+qp1+qp2+qp3) ----------------
__global__ void k_qfin(const float* __restrict__ dinvU, const float* __restrict__ qp,
                       float* __restrict__ q) {
  int i = blockIdx.x*256 + threadIdx.x;
  if (i < BNODES)
    q[i] = dinvU[i]*(qp[i] + qp[BNODES + i] + qp[2*BNODES + i] + qp[3*BNODES + i]);
}

// ---------------- scoring aggregation: graph's q staged in LDS ----------------
__global__ void k_score(const int* __restrict__ rowptr, const int2* __restrict__ csr_sw,
                        const float* __restrict__ dinvU, const float* __restrict__ q,
                        const float* __restrict__ bp, float* __restrict__ score) {
  __shared__ float sQ[NN];
  int t = threadIdx.x;
  int l16 = t & 15;
  int d = blockIdx.x*16 + (t >> 4);
  int gbase = d & ~(NN-1);               // all 16 nodes in same graph (1024%16==0)
  #pragma unroll
  for (int i = 0; i < 4; ++i) sQ[i*256 + t] = q[gbase + i*256 + t];
  __syncthreads();
  float du = dinvU[d];
  float sum = 0.f;
  if (du != 0.f) {
    int r0 = rowptr[d], r1 = rowptr[d+1];
    for (int base = r0; base < r1; base += 16)
      if (base + l16 < r1) sum += sQ[csr_sw[base + l16].x - gbase];
  }
  #pragma unroll
  for (int off = 8; off; off >>= 1) sum += __shfl_xor(sum, off, 16);
  if (l16 == 0) score[d] = bp[0] + du*(sQ[d - gbase] + sum);
}

// ---------------- top-k rank: 4 blocks/graph; alive test = dinvU != 0 ----------------
__global__ void k_topk(const float* __restrict__ score,
                       const float* __restrict__ dinvU, int k,
                       float* __restrict__ tm, int* __restrict__ aliveN) {
  __shared__ float sc[NN];
  int b = blockIdx.x >> 2, p = blockIdx.x & 3;
  int t = threadIdx.x;
  int gbase = b*NN;
  #pragma unroll
  for (int i = 0; i < 4; ++i) {
    int n = i*256 + t;
    sc[n] = (dinvU[gbase + n] != 0.f) ? score[gbase + n] : -INFINITY;
  }
  __syncthreads();
  int n = p*256 + t;              // this thread's node
  int node = gbase + n;
  float me = sc[n];
  float raw = score[node];
  int rank = 0;
  const float4* sc4 = (const float4*)sc;
  for (int j4 = 0; j4 < NN/4; ++j4) {
    float4 o = sc4[j4];
    int jb = j4*4;
    rank += (o.x > me) || (o.x == me && jb+0 < n);
    rank += (o.y > me) || (o.y == me && jb+1 < n);
    rank += (o.z > me) || (o.z == me && jb+2 < n);
    rank += (o.w > me) || (o.w == me && jb+3 < n);
  }
  int sel = (rank < k) ? 1 : 0;
  aliveN[node] = sel;
  tm[node] = sel ? tanhf(raw) : 0.f;
}

// ---------------- fused readout partials + pool-scale GEMM + NEXT-layer degrees ----------------
// Graph's full alive mask staged in LDS (1 KB) -> degs walk is LDS-local.
template<bool DOLIN, int DEGMODE>
__global__ void k_srl(const float* __restrict__ hA, const float* __restrict__ tm,
                      const int* __restrict__ aliveN, const float* __restrict__ W,
                      float* __restrict__ hB,
                      float* __restrict__ pmax, float* __restrict__ psum,
                      const int* __restrict__ rowptr, const int2* __restrict__ csr_sw,
                      float* __restrict__ dinvW, float* __restrict__ dinvU) {
  __shared__ float sX[64][65];
  __shared__ float sW[64*64];
  __shared__ float sTm[64];
  __shared__ unsigned char sAlG[NN];     // whole graph's alive mask (1 KB)
  __shared__ float rm[4][FH], rs[4][FH];
  int t = threadIdx.x;
  int blk = blockIdx.x;
  int nb = blk*64;
  int gbase = (blk >> 4) * NN;           // 16 blocks per graph
  if (DOLIN)
    for (int i = t; i < 1024; i += 256) ((float4*)sW)[i] = ((const float4*)W)[i];
  if (t < 64) sTm[t] = tm[nb + t];
  #pragma unroll
  for (int i = 0; i < 4; ++i) {
    int n = i*256 + t;
    sAlG[n] = (unsigned char)aliveN[gbase + n];
  }
  __syncthreads();
  int lb = nb - gbase;                   // local node base 0..960
  // stage sX = tm * hA (quarter-major source)
  #pragma unroll
  for (int q = 0; q < 4; ++q) {
    const float* hq = hA + (size_t)q*BNODES*16 + (size_t)nb*16;
    #pragma unroll
    for (int i = 0; i < 4; ++i) {
      int idx = i*256 + t;          // 1024 floats = 64 nodes x 16
      int n = idx >> 4, ff = idx & 15;
      sX[n][q*16 + ff] = hq[idx] * sTm[n];
    }
  }
  __syncthreads();
  {
    int f = t & 63, r = t >> 6;
    float mx = -INFINITY, sm = 0.f;
    #pragma unroll
    for (int i = 0; i < 16; ++i) {
      int n = r + i*4;
      float v = sX[n][f];
      if (sAlG[lb + n]) { mx = fmaxf(mx, v); sm += v; }
    }
    rm[r][f] = mx; rs[r][f] = sm;
  }
  __syncthreads();
  if (t < FH) {
    float m2 = fmaxf(fmaxf(rm[0][t], rm[1][t]), fmaxf(rm[2][t], rm[3][t]));
    float s2 = rs[0][t] + rs[1][t] + rs[2][t] + rs[3][t];
    pmax[blk*FH + t] = m2;
    psum[blk*FH + t] = s2;
  }
  // ---- next-layer degrees (alive mask in LDS; overlaps GEMM across waves) ----
  if (DEGMODE != 0) {
    int g = t >> 4, l16 = t & 15;       // 16 groups x 16 lanes
    for (int i = 0; i < 4; ++i) {
      int n = g*4 + i;                  // local node 0..63
      int d = nb + n;
      int r0 = rowptr[d], r1 = rowptr[d+1];
      float sWd = 0.f, sU = 0.f;
      for (int base = r0; base < r1; base += 16) {
        if (base + l16 < r1) {
          int2 p = csr_sw[base + l16];
          if (sAlG[p.x - gbase]) {
            sWd += (DEGMODE == 2) ? 1.f : __int_as_float(p.y);
            sU += 1.f;
          }
        }
      }
      #pragma unroll
      for (int off = 8; off; off >>= 1) {
        sWd += __shfl_xor(sWd, off, 16);
        sU  += __shfl_xor(sU, off, 16);
      }
      if (l16 == 0) {
        bool dA = (sAlG[lb + n] != 0);
        dinvW[d] = dA ? rsqrtf(1.f + sWd) : 0.f;
        dinvU[d] = dA ? rsqrtf(1.f + sU) : 0.f;
      }
    }
  }
  if (DOLIN) {
    int node = t >> 2;
    int quarter = t & 3;
    int f0 = quarter * 16;
    float4 a0 = {0,0,0,0}, a1 = a0, a2 = a0, a3 = a0;
    #pragma unroll 4
    for (int k = 0; k < 64; ++k) {
      float xv = sX[node][k];
      const float4 w0 = *(const float4*)&sW[k*64 + f0];
      const float4 w1 = *(const float4*)&sW[k*64 + f0 + 4];
      const float4 w2 = *(const float4*)&sW[k*64 + f0 + 8];
      const float4 w3 = *(const float4*)&sW[k*64 + f0 + 12];
      a0.x = fmaf(xv, w0.x, a0.x); a0.y = fmaf(xv, w0.y, a0.y);
      a0.z = fmaf(xv, w0.z, a0.z); a0.w = fmaf(xv, w0.w, a0.w);
      a1.x = fmaf(xv, w1.x, a1.x); a1.y = fmaf(xv, w1.y, a1.y);
      a1.z = fmaf(xv, w1.z, a1.z); a1.w = fmaf(xv, w1.w, a1.w);
      a2.x = fmaf(xv, w2.x, a2.x); a2.y = fmaf(xv, w2.y, a2.y);
      a2.z = fmaf(xv, w2.z, a2.z); a2.w = fmaf(xv, w2.w, a2.w);
      a3.x = fmaf(xv, w3.x, a3.x); a3.y = fmaf(xv, w3.y, a3.y);
      a3.z = fmaf(xv, w3.z, a3.z); a3.w = fmaf(xv, w3.w, a3.w);
    }
    // quarter-major hB write: [quarter][node][16]
    float4* dst = (float4*)(hB + (size_t)quarter*BNODES*16 + (size_t)(nb + node)*16);
    dst[0] = a0; dst[1] = a1; dst[2] = a2; dst[3] = a3;
  }
}

// ---------------- partial reduce + MLP head + log_softmax ----------------
__global__ void k_mlp(const float* __restrict__ pmax, const float* __restrict__ psum,
                      const float* __restrict__ Wl1, const float* __restrict__ bl1,
                      const float* __restrict__ Wl2, const float* __restrict__ bl2,
                      const float* __restrict__ Wl3, const float* __restrict__ bl3,
                      float* __restrict__ out) {
  __shared__ float sg[2*FH];
  __shared__ float l1[FH];
  __shared__ float l2[FH/2];
  __shared__ float l3[2];
  int b = blockIdx.x, t = threadIdx.x;
  const float kf[3] = {(float)KK1, (float)KK2, (float)KK3};
  float gm = 0.f, gs = 0.f;
  #pragma unroll
  for (int l = 0; l < 3; ++l) {
    const float* pm = pmax + (size_t)l*NB*16*FH + (b*16)*FH;
    const float* ps = psum + (size_t)l*NB*16*FH + (b*16)*FH;
    float mm = -INFINITY, ss = 0.f;
    #pragma unroll
    for (int p = 0; p < 16; ++p) {
      mm = fmaxf(mm, pm[p*FH + t]);
      ss += ps[p*FH + t];
    }
    gm += mm;
    gs += ss / kf[l];
  }
  sg[t] = gm;
  sg[FH + t] = gs;
  __syncthreads();
  float acc = bl1[t];
  #pragma unroll
  for (int k = 0; k < 2*FH; ++k) acc = fmaf(sg[k], Wl1[k*FH + t], acc);
  l1[t] = fmaxf(acc, 0.f);
  __syncthreads();
  if (t < 32) {
    float a2 = bl2[t];
    #pragma unroll
    for (int k = 0; k < FH; ++k) a2 = fmaf(l1[k], Wl2[k*32 + t], a2);
    l2[t] = fmaxf(a2, 0.f);
  }
  __syncthreads();
  if (t < 2) {
    float a3 = bl3[t];
    #pragma unroll
    for (int k = 0; k < 32; ++k) a3 = fmaf(l2[k], Wl3[k*2 + t], a3);
    l3[t] = a3;
  }
  __syncthreads();
  if (t == 0) {
    float m = fmaxf(l3[0], l3[1]);
    float lse = m + logf(expf(l3[0]-m) + expf(l3[1]-m));
    out[b*2+0] = l3[0] - lse;
    out[b*2+1] = l3[1] - lse;
  }
}

extern "C" void kernel_launch(void* const* d_in, const int* in_sizes, int n_in,
                              void* d_out, int out_size, void* d_ws, size_t ws_size,
                              hipStream_t stream) {
  const float* x   = (const float*)d_in[0];
  const float* ea  = (const float*)d_in[1];
  const float* W1  = (const float*)d_in[2];
  const float* b1  = (const float*)d_in[3];
  const float* Wp1 = (const float*)d_in[4];
  const float* bp1 = (const float*)d_in[5];
  const float* W2  = (const float*)d_in[6];
  const float* b2  = (const float*)d_in[7];
  const float* Wp2 = (const float*)d_in[8];
  const float* bp2 = (const float*)d_in[9];
  const float* W3  = (const float*)d_in[10];
  const float* b3  = (const float*)d_in[11];
  const float* Wp3 = (const float*)d_in[12];
  const float* bp3 = (const float*)d_in[13];
  const float* Wl1 = (const float*)d_in[14];
  const float* bl1 = (const float*)d_in[15];
  const float* Wl2 = (const float*)d_in[16];
  const float* bl2 = (const float*)d_in[17];
  const float* Wl3 = (const float*)d_in[18];
  const float* bl3 = (const float*)d_in[19];
  const int*   ei  = (const int*)d_in[20];
  float* out = (float*)d_out;

  int2* csr_sw = (int2*)d_ws;                        // NE
  float* hA    = (float*)(csr_sw + NE);              // BNODES*FH (quarter-major)
  float* hB    = hA + (size_t)BNODES*FH;             // BNODES*FH (quarter-major)
  float* dinvW = hB + (size_t)BNODES*FH;             // BNODES
  float* dinvU = dinvW + BNODES;                     // BNODES
  float* qpart = dinvU + BNODES;                     // 4*BNODES
  float* q     = qpart + 4*BNODES;                   // BNODES
  float* score = q + BNODES;                         // BNODES
  float* tm    = score + BNODES;                     // BNODES
  float* pmax  = tm + BNODES;                        // 3*NB*16*FH
  float* psum  = pmax + 3*NB*16*FH;                  // 3*NB*16*FH
  int* aliveN  = (int*)(psum + 3*NB*16*FH);          // BNODES
  int* rowptr  = aliveN + BNODES;                    // BNODES+1

  const size_t gathLds = (size_t)NN*16*sizeof(float);   // 64 KB
  const int gS = BNODES/64;                             // 2048 srl blocks
  const int gG = BNODES/16;                             // 8192 score blocks
  const int gN = BNODES/256;                            // 512

  k_csr<<<NB, 1024, EPG*sizeof(int2), stream>>>(ei, ea, rowptr, csr_sw, dinvW, dinvU);

  // ===== Layer 1 =====
  k_gath<0,true><<<NB*4, 1024, gathLds, stream>>>(rowptr, csr_sw, dinvW, x, W1, b1, Wp1, hA, qpart);
  k_qfin<<<gN, 256, 0, stream>>>(dinvU, qpart, q);
  k_score<<<gG, 256, 0, stream>>>(rowptr, csr_sw, dinvU, q, bp1, score);
  k_topk<<<NB*4, 256, 0, stream>>>(score, dinvU, KK1, tm, aliveN);
  k_srl<true,1><<<gS, 256, 0, stream>>>(hA, tm, aliveN, W2, hB, pmax, psum,
                                        rowptr, csr_sw, dinvW, dinvU);

  // ===== Layer 2 =====
  k_gath<1,false><<<NB*4, 1024, gathLds, stream>>>(rowptr, csr_sw, dinvW, hB, W1, b2, Wp2, hA, qpart);
  k_qfin<<<gN, 256, 0, stream>>>(dinvU, qpart, q);
  k_score<<<gG, 256, 0, stream>>>(rowptr, csr_sw, dinvU, q, bp2, score);
  k_topk<<<NB*4, 256, 0, stream>>>(score, dinvU, KK2, tm, aliveN);
  k_srl<true,2><<<gS, 256, 0, stream>>>(hA, tm, aliveN, W3, hB, pmax + NB*16*FH, psum + NB*16*FH,
                                        rowptr, csr_sw, dinvW, dinvU);

  // ===== Layer 3 =====
  k_gath<2,false><<<NB*4, 1024, gathLds, stream>>>(rowptr, csr_sw, dinvW, hB, W1, b3, Wp3, hA, qpart);
  k_qfin<<<gN, 256, 0, stream>>>(dinvU, qpart, q);
  k_score<<<gG, 256, 0, stream>>>(rowptr, csr_sw, dinvU, q, bp3, score);
  k_topk<<<NB*4, 256, 0, stream>>>(score, dinvU, KK3, tm, aliveN);
  k_srl<false,0><<<gS, 256, 0, stream>>>(hA, tm, aliveN, W3, hB, pmax + 2*NB*16*FH, psum + 2*NB*16*FH,
                                         rowptr, csr_sw, dinvW, dinvU);

  k_mlp<<<NB, FH, 0, stream>>>(pmax, psum, Wl1, bl1, Wl2, bl2, Wl3, bl3, out);
}

// Round 27
// 362.582 us; speedup vs baseline: 1.0820x; 1.0019x over previous
//
#include <hip/hip_runtime.h>
#include <math.h>

#define NB 128            // graphs
#define NN 1024           // nodes per graph
#define BNODES (NB*NN)    // 131072
#define NE 2097152        // edges
#define EPG (NE/NB)       // 16384 edges per graph (edge list is graph-blocked)
#define EPT (EPG/NN)      // 16 edges per thread in k_csr
#define FH 64             // hidden
#define KK1 820
#define KK2 656
#define KK3 525

// ---------------- one-kernel CSR build + layer-1 degrees ----------------
__global__ __launch_bounds__(1024) void k_csr(const int* __restrict__ ei,
                                              const float* __restrict__ ea,
                                              int* __restrict__ rowptr,
                                              int2* __restrict__ csr_sw,
                                              float* __restrict__ dinvW,
                                              float* __restrict__ dinvU) {
  extern __shared__ int2 lcsr[];          // EPG entries = 128 KB
  __shared__ int cnt[NN];
  __shared__ int cur[NN];
  __shared__ float wsum[NN];
  int b = blockIdx.x, t = threadIdx.x;
  int node = b*NN + t;
  cnt[t] = 0;
  wsum[t] = 0.f;
  __syncthreads();
  int ebase = b*EPG;
  int se[EPT]; int de[EPT]; float we[EPT];
  #pragma unroll
  for (int i = 0; i < EPT; ++i) {
    int e = ebase + i*NN + t;
    se[i] = ei[e];
    de[i] = ei[NE + e] - b*NN;
    we[i] = ea[e];
    atomicAdd(&cnt[de[i]], 1);
    atomicAdd(&wsum[de[i]], we[i]);
  }
  __syncthreads();
  int v = cnt[t];
  for (int off = 1; off < NN; off <<= 1) {
    int u = (t >= off) ? cnt[t - off] : 0;
    __syncthreads();
    cnt[t] += u;
    __syncthreads();
  }
  int excl = cnt[t] - v;
  rowptr[node] = ebase + excl;
  cur[t] = excl;
  dinvW[node] = rsqrtf(1.f + wsum[t]);    // layer-1 weighted degree (all alive)
  dinvU[node] = rsqrtf(1.f + (float)v);   // layer-1 unweighted degree
  if (b == NB-1 && t == NN-1) rowptr[BNODES] = NE;
  __syncthreads();
  #pragma unroll
  for (int i = 0; i < EPT; ++i) {
    int pos = atomicAdd(&cur[de[i]], 1);
    lcsr[pos] = make_int2(se[i], __float_as_int(we[i]));
  }
  __syncthreads();
  float4* dst4 = (float4*)(csr_sw + ebase);
  const float4* src4 = (const float4*)lcsr;
  #pragma unroll
  for (int i = 0; i < EPG/2/NN; ++i)
    dst4[i*NN + t] = src4[i*NN + t];
}

// ---------------- LDS-staged GCN gather: 1 block per (graph, feature-QUARTER) ----------------
// blockIdx = quarter*NB + b -> all 4 slices of graph b co-located per XCD.
// Inner loop: chunks of 8 register-prefetched edges (independent L2 loads),
// masked by c=0; index clamp &(NN-1) keeps LDS in-bounds at graph end.
template<int MODE, bool L1S>
__global__ __launch_bounds__(1024, 4) void k_gath(
    const int* __restrict__ rowptr, const int2* __restrict__ csr_sw,
    const float* __restrict__ dinvW, const float* __restrict__ src,  // hBq or x
    const float* __restrict__ Wl,                                    // W1 (L1S only)
    const float* __restrict__ bias, const float* __restrict__ Wp,
    float* __restrict__ hA, float* __restrict__ qpart) {
  extern __shared__ float sHB[];        // [NN][16] = 64 KB
  __shared__ float sDW[NN];
  __shared__ float sWp[16];
  __shared__ float sB[16];
  __shared__ float sW1[32];
  int b = blockIdx.x & (NB-1), quarter = blockIdx.x >> 7;
  int t = threadIdx.x, l4 = t & 3;
  int gbase = b*NN;
  sDW[t] = dinvW[gbase + t];
  if (t < 16) { sWp[t] = Wp[quarter*16 + t]; sB[t] = bias[quarter*16 + t]; }
  float4* sHB4 = (float4*)sHB;
  if (L1S) {
    if (t < 16) { sW1[t] = Wl[quarter*16 + t]; sW1[16 + t] = Wl[64 + quarter*16 + t]; }
    __syncthreads();
    #pragma unroll
    for (int i = 0; i < 16; ++i) {
      int el = i*1024 + t;               // 16384 floats
      int n = el >> 4, ff = el & 15;
      float x0 = src[(size_t)(gbase + n)*2];
      float x1 = src[(size_t)(gbase + n)*2 + 1];
      sHB[n*16 + ff] = x0*sW1[ff] + x1*sW1[16 + ff];
    }
  } else {
    const float4* hq4 = (const float4*)src + (size_t)quarter*BNODES*4 + (size_t)gbase*4;
    #pragma unroll
    for (int i = 0; i < 4; ++i) {
      int idx = i*1024 + t;              // 4096 float4 = 64 KB
      sHB4[idx] = hq4[idx];
    }
  }
  __syncthreads();
  float4 bv = ((const float4*)sB)[l4];
  float4 wp = ((const float4*)sWp)[l4];
  #pragma unroll 1
  for (int pass = 0; pass < 4; ++pass) {
    int n = pass*256 + (t >> 2);
    int gn = gbase + n;
    float dd = sDW[n];
    float4 hv = sHB4[n*4 + l4];
    float dd2 = dd*dd;
    float4 acc;
    acc.x = fmaf(dd2, hv.x, bv.x);
    acc.y = fmaf(dd2, hv.y, bv.y);
    acc.z = fmaf(dd2, hv.z, bv.z);
    acc.w = fmaf(dd2, hv.w, bv.w);
    int r0 = rowptr[gn], r1 = rowptr[gn+1];
    #pragma unroll 1
    for (int base = r0; base < r1; base += 8) {
      int2 pe[8];
      #pragma unroll
      for (int j = 0; j < 8; ++j)
        pe[j] = csr_sw[min(base + j, NE-1)];   // 8 independent L2 loads
      #pragma unroll
      for (int j = 0; j < 8; ++j) {
        bool ok = (base + j) < r1;
        int sl = (pe[j].x - gbase) & (NN-1);   // clamp keeps LDS in-bounds
        float w = (MODE == 2) ? 1.f : __int_as_float(pe[j].y);
        float c = ok ? dd * sDW[sl] * w : 0.f; // 0 if masked or dead
        float4 v = sHB4[sl*4 + l4];
        acc.x = fmaf(c, v.x, acc.x);
        acc.y = fmaf(c, v.y, acc.y);
        acc.z = fmaf(c, v.z, acc.z);
        acc.w = fmaf(c, v.w, acc.w);
      }
    }
    acc.x = fmaxf(acc.x, 0.f); acc.y = fmaxf(acc.y, 0.f);
    acc.z = fmaxf(acc.z, 0.f); acc.w = fmaxf(acc.w, 0.f);
    ((float4*)hA)[(size_t)quarter*BNODES*4 + (size_t)gn*4 + l4] = acc;  // quarter-major
    float dot = acc.x*wp.x + acc.y*wp.y + acc.z*wp.z + acc.w*wp.w;
    dot += __shfl_xor(dot, 2, 4);
    dot += __shfl_xor(dot, 1, 4);
    if (l4 == 0) qpart[quarter*BNODES + gn] = dot;
  }
}

// ---------------- q finalize: q = dinvU * (qp0+qp1+qp2+qp3) ----------------
__global__ void k_qfin(const float* __restrict__ dinvU, const float* __restrict__ qp,
                       float* __restrict__ q) {
  int i = blockIdx.x*256 + threadIdx.x;
  if (i < BNODES)
    q[i] = dinvU[i]*(qp[i] + qp[BNODES + i] + qp[2*BNODES + i] + qp[3*BNODES + i]);
}

// ---------------- scoring aggregation: graph's q staged in LDS ----------------
__global__ void k_score(const int* __restrict__ rowptr, const int2* __restrict__ csr_sw,
                        const float* __restrict__ dinvU, const float* __restrict__ q,
                        const float* __restrict__ bp, float* __restrict__ score) {
  __shared__ float sQ[NN];
  int t = threadIdx.x;
  int l16 = t & 15;
  int d = blockIdx.x*16 + (t >> 4);
  int gbase = d & ~(NN-1);               // all 16 nodes in same graph (1024%16==0)
  #pragma unroll
  for (int i = 0; i < 4; ++i) sQ[i*256 + t] = q[gbase + i*256 + t];
  __syncthreads();
  float du = dinvU[d];
  float sum = 0.f;
  if (du != 0.f) {
    int r0 = rowptr[d], r1 = rowptr[d+1];
    for (int base = r0; base < r1; base += 16)
      if (base + l16 < r1) sum += sQ[csr_sw[base + l16].x - gbase];
  }
  #pragma unroll
  for (int off = 8; off; off >>= 1) sum += __shfl_xor(sum, off, 16);
  if (l16 == 0) score[d] = bp[0] + du*(sQ[d - gbase] + sum);
}

// ---------------- top-k rank: 4 blocks/graph; alive test = dinvU != 0 ----------------
__global__ void k_topk(const float* __restrict__ score,
                       const float* __restrict__ dinvU, int k,
                       float* __restrict__ tm, int* __restrict__ aliveN) {
  __shared__ float sc[NN];
  int b = blockIdx.x >> 2, p = blockIdx.x & 3;
  int t = threadIdx.x;
  int gbase = b*NN;
  #pragma unroll
  for (int i = 0; i < 4; ++i) {
    int n = i*256 + t;
    sc[n] = (dinvU[gbase + n] != 0.f) ? score[gbase + n] : -INFINITY;
  }
  __syncthreads();
  int n = p*256 + t;              // this thread's node
  int node = gbase + n;
  float me = sc[n];
  float raw = score[node];
  int rank = 0;
  const float4* sc4 = (const float4*)sc;
  for (int j4 = 0; j4 < NN/4; ++j4) {
    float4 o = sc4[j4];
    int jb = j4*4;
    rank += (o.x > me) || (o.x == me && jb+0 < n);
    rank += (o.y > me) || (o.y == me && jb+1 < n);
    rank += (o.z > me) || (o.z == me && jb+2 < n);
    rank += (o.w > me) || (o.w == me && jb+3 < n);
  }
  int sel = (rank < k) ? 1 : 0;
  aliveN[node] = sel;
  tm[node] = sel ? tanhf(raw) : 0.f;
}

// ---------------- fused readout partials + pool-scale GEMM + NEXT-layer degrees ----------------
// Graph's full alive mask staged in LDS (1 KB) -> degs walk is LDS-local.
template<bool DOLIN, int DEGMODE>
__global__ void k_srl(const float* __restrict__ hA, const float* __restrict__ tm,
                      const int* __restrict__ aliveN, const float* __restrict__ W,
                      float* __restrict__ hB,
                      float* __restrict__ pmax, float* __restrict__ psum,
                      const int* __restrict__ rowptr, const int2* __restrict__ csr_sw,
                      float* __restrict__ dinvW, float* __restrict__ dinvU) {
  __shared__ float sX[64][65];
  __shared__ float sW[64*64];
  __shared__ float sTm[64];
  __shared__ unsigned char sAlG[NN];     // whole graph's alive mask (1 KB)
  __shared__ float rm[4][FH], rs[4][FH];
  int t = threadIdx.x;
  int blk = blockIdx.x;
  int nb = blk*64;
  int gbase = (blk >> 4) * NN;           // 16 blocks per graph
  if (DOLIN)
    for (int i = t; i < 1024; i += 256) ((float4*)sW)[i] = ((const float4*)W)[i];
  if (t < 64) sTm[t] = tm[nb + t];
  #pragma unroll
  for (int i = 0; i < 4; ++i) {
    int n = i*256 + t;
    sAlG[n] = (unsigned char)aliveN[gbase + n];
  }
  __syncthreads();
  int lb = nb - gbase;                   // local node base 0..960
  // stage sX = tm * hA (quarter-major source)
  #pragma unroll
  for (int q = 0; q < 4; ++q) {
    const float* hq = hA + (size_t)q*BNODES*16 + (size_t)nb*16;
    #pragma unroll
    for (int i = 0; i < 4; ++i) {
      int idx = i*256 + t;          // 1024 floats = 64 nodes x 16
      int n = idx >> 4, ff = idx & 15;
      sX[n][q*16 + ff] = hq[idx] * sTm[n];
    }
  }
  __syncthreads();
  {
    int f = t & 63, r = t >> 6;
    float mx = -INFINITY, sm = 0.f;
    #pragma unroll
    for (int i = 0; i < 16; ++i) {
      int n = r + i*4;
      float v = sX[n][f];
      if (sAlG[lb + n]) { mx = fmaxf(mx, v); sm += v; }
    }
    rm[r][f] = mx; rs[r][f] = sm;
  }
  __syncthreads();
  if (t < FH) {
    float m2 = fmaxf(fmaxf(rm[0][t], rm[1][t]), fmaxf(rm[2][t], rm[3][t]));
    float s2 = rs[0][t] + rs[1][t] + rs[2][t] + rs[3][t];
    pmax[blk*FH + t] = m2;
    psum[blk*FH + t] = s2;
  }
  // ---- next-layer degrees (alive mask in LDS; overlaps GEMM across waves) ----
  if (DEGMODE != 0) {
    int g = t >> 4, l16 = t & 15;       // 16 groups x 16 lanes
    for (int i = 0; i < 4; ++i) {
      int n = g*4 + i;                  // local node 0..63
      int d = nb + n;
      int r0 = rowptr[d], r1 = rowptr[d+1];
      float sWd = 0.f, sU = 0.f;
      for (int base = r0; base < r1; base += 16) {
        if (base + l16 < r1) {
          int2 p = csr_sw[base + l16];
          if (sAlG[p.x - gbase]) {
            sWd += (DEGMODE == 2) ? 1.f : __int_as_float(p.y);
            sU += 1.f;
          }
        }
      }
      #pragma unroll
      for (int off = 8; off; off >>= 1) {
        sWd += __shfl_xor(sWd, off, 16);
        sU  += __shfl_xor(sU, off, 16);
      }
      if (l16 == 0) {
        bool dA = (sAlG[lb + n] != 0);
        dinvW[d] = dA ? rsqrtf(1.f + sWd) : 0.f;
        dinvU[d] = dA ? rsqrtf(1.f + sU) : 0.f;
      }
    }
  }
  if (DOLIN) {
    int node = t >> 2;
    int quarter = t & 3;
    int f0 = quarter * 16;
    float4 a0 = {0,0,0,0}, a1 = a0, a2 = a0, a3 = a0;
    #pragma unroll 4
    for (int k = 0; k < 64; ++k) {
      float xv = sX[node][k];
      const float4 w0 = *(const float4*)&sW[k*64 + f0];
      const float4 w1 = *(const float4*)&sW[k*64 + f0 + 4];
      const float4 w2 = *(const float4*)&sW[k*64 + f0 + 8];
      const float4 w3 = *(const float4*)&sW[k*64 + f0 + 12];
      a0.x = fmaf(xv, w0.x, a0.x); a0.y = fmaf(xv, w0.y, a0.y);
      a0.z = fmaf(xv, w0.z, a0.z); a0.w = fmaf(xv, w0.w, a0.w);
      a1.x = fmaf(xv, w1.x, a1.x); a1.y = fmaf(xv, w1.y, a1.y);
      a1.z = fmaf(xv, w1.z, a1.z); a1.w = fmaf(xv, w1.w, a1.w);
      a2.x = fmaf(xv, w2.x, a2.x); a2.y = fmaf(xv, w2.y, a2.y);
      a2.z = fmaf(xv, w2.z, a2.z); a2.w = fmaf(xv, w2.w, a2.w);
      a3.x = fmaf(xv, w3.x, a3.x); a3.y = fmaf(xv, w3.y, a3.y);
      a3.z = fmaf(xv, w3.z, a3.z); a3.w = fmaf(xv, w3.w, a3.w);
    }
    // quarter-major hB write: [quarter][node][16]
    float4* dst = (float4*)(hB + (size_t)quarter*BNODES*16 + (size_t)(nb + node)*16);
    dst[0] = a0; dst[1] = a1; dst[2] = a2; dst[3] = a3;
  }
}

// ---------------- partial reduce + MLP head + log_softmax ----------------
__global__ void k_mlp(const float* __restrict__ pmax, const float* __restrict__ psum,
                      const float* __restrict__ Wl1, const float* __restrict__ bl1,
                      const float* __restrict__ Wl2, const float* __restrict__ bl2,
                      const float* __restrict__ Wl3, const float* __restrict__ bl3,
                      float* __restrict__ out) {
  __shared__ float sg[2*FH];
  __shared__ float l1[FH];
  __shared__ float l2[FH/2];
  __shared__ float l3[2];
  int b = blockIdx.x, t = threadIdx.x;
  const float kf[3] = {(float)KK1, (float)KK2, (float)KK3};
  float gm = 0.f, gs = 0.f;
  #pragma unroll
  for (int l = 0; l < 3; ++l) {
    const float* pm = pmax + (size_t)l*NB*16*FH + (b*16)*FH;
    const float* ps = psum + (size_t)l*NB*16*FH + (b*16)*FH;
    float mm = -INFINITY, ss = 0.f;
    #pragma unroll
    for (int p = 0; p < 16; ++p) {
      mm = fmaxf(mm, pm[p*FH + t]);
      ss += ps[p*FH + t];
    }
    gm += mm;
    gs += ss / kf[l];
  }
  sg[t] = gm;
  sg[FH + t] = gs;
  __syncthreads();
  float acc = bl1[t];
  #pragma unroll
  for (int k = 0; k < 2*FH; ++k) acc = fmaf(sg[k], Wl1[k*FH + t], acc);
  l1[t] = fmaxf(acc, 0.f);
  __syncthreads();
  if (t < 32) {
    float a2 = bl2[t];
    #pragma unroll
    for (int k = 0; k < FH; ++k) a2 = fmaf(l1[k], Wl2[k*32 + t], a2);
    l2[t] = fmaxf(a2, 0.f);
  }
  __syncthreads();
  if (t < 2) {
    float a3 = bl3[t];
    #pragma unroll
    for (int k = 0; k < 32; ++k) a3 = fmaf(l2[k], Wl3[k*2 + t], a3);
    l3[t] = a3;
  }
  __syncthreads();
  if (t == 0) {
    float m = fmaxf(l3[0], l3[1]);
    float lse = m + logf(expf(l3[0]-m) + expf(l3[1]-m));
    out[b*2+0] = l3[0] - lse;
    out[b*2+1] = l3[1] - lse;
  }
}

extern "C" void kernel_launch(void* const* d_in, const int* in_sizes, int n_in,
                              void* d_out, int out_size, void* d_ws, size_t ws_size,
                              hipStream_t stream) {
  const float* x   = (const float*)d_in[0];
  const float* ea  = (const float*)d_in[1];
  const float* W1  = (const float*)d_in[2];
  const float* b1  = (const float*)d_in[3];
  const float* Wp1 = (const float*)d_in[4];
  const float* bp1 = (const float*)d_in[5];
  const float* W2  = (const float*)d_in[6];
  const float* b2  = (const float*)d_in[7];
  const float* Wp2 = (const float*)d_in[8];
  const float* bp2 = (const float*)d_in[9];
  const float* W3  = (const float*)d_in[10];
  const float* b3  = (const float*)d_in[11];
  const float* Wp3 = (const float*)d_in[12];
  const float* bp3 = (const float*)d_in[13];
  const float* Wl1 = (const float*)d_in[14];
  const float* bl1 = (const float*)d_in[15];
  const float* Wl2 = (const float*)d_in[16];
  const float* bl2 = (const float*)d_in[17];
  const float* Wl3 = (const float*)d_in[18];
  const float* bl3 = (const float*)d_in[19];
  const int*   ei  = (const int*)d_in[20];
  float* out = (float*)d_out;

  int2* csr_sw = (int2*)d_ws;                        // NE
  float* hA    = (float*)(csr_sw + NE);              // BNODES*FH (quarter-major)
  float* hB    = hA + (size_t)BNODES*FH;             // BNODES*FH (quarter-major)
  float* dinvW = hB + (size_t)BNODES*FH;             // BNODES
  float* dinvU = dinvW + BNODES;                     // BNODES
  float* qpart = dinvU + BNODES;                     // 4*BNODES
  float* q     = qpart + 4*BNODES;                   // BNODES
  float* score = q + BNODES;                         // BNODES
  float* tm    = score + BNODES;                     // BNODES
  float* pmax  = tm + BNODES;                        // 3*NB*16*FH
  float* psum  = pmax + 3*NB*16*FH;                  // 3*NB*16*FH
  int* aliveN  = (int*)(psum + 3*NB*16*FH);          // BNODES
  int* rowptr  = aliveN + BNODES;                    // BNODES+1

  const size_t gathLds = (size_t)NN*16*sizeof(float);   // 64 KB
  const int gS = BNODES/64;                             // 2048 srl blocks
  const int gG = BNODES/16;                             // 8192 score blocks
  const int gN = BNODES/256;                            // 512

  k_csr<<<NB, 1024, EPG*sizeof(int2), stream>>>(ei, ea, rowptr, csr_sw, dinvW, dinvU);

  // ===== Layer 1 =====
  k_gath<0,true><<<NB*4, 1024, gathLds, stream>>>(rowptr, csr_sw, dinvW, x, W1, b1, Wp1, hA, qpart);
  k_qfin<<<gN, 256, 0, stream>>>(dinvU, qpart, q);
  k_score<<<gG, 256, 0, stream>>>(rowptr, csr_sw, dinvU, q, bp1, score);
  k_topk<<<NB*4, 256, 0, stream>>>(score, dinvU, KK1, tm, aliveN);
  k_srl<true,1><<<gS, 256, 0, stream>>>(hA, tm, aliveN, W2, hB, pmax, psum,
                                        rowptr, csr_sw, dinvW, dinvU);

  // ===== Layer 2 =====
  k_gath<1,false><<<NB*4, 1024, gathLds, stream>>>(rowptr, csr_sw, dinvW, hB, W1, b2, Wp2, hA, qpart);
  k_qfin<<<gN, 256, 0, stream>>>(dinvU, qpart, q);
  k_score<<<gG, 256, 0, stream>>>(rowptr, csr_sw, dinvU, q, bp2, score);
  k_topk<<<NB*4, 256, 0, stream>>>(score, dinvU, KK2, tm, aliveN);
  k_srl<true,2><<<gS, 256, 0, stream>>>(hA, tm, aliveN, W3, hB, pmax + NB*16*FH, psum + NB*16*FH,
                                        rowptr, csr_sw, dinvW, dinvU);

  // ===== Layer 3 =====
  k_gath<2,false><<<NB*4, 1024, gathLds, stream>>>(rowptr, csr_sw, dinvW, hB, W1, b3, Wp3, hA, qpart);
  k_qfin<<<gN, 256, 0, stream>>>(dinvU, qpart, q);
  k_score<<<gG, 256, 0, stream>>>(rowptr, csr_sw, dinvU, q, bp3, score);
  k_topk<<<NB*4, 256, 0, stream>>>(score, dinvU, KK3, tm, aliveN);
  k_srl<false,0><<<gS, 256, 0, stream>>>(hA, tm, aliveN, W3, hB, pmax + 2*NB*16*FH, psum + 2*NB*16*FH,
                                         rowptr, csr_sw, dinvW, dinvU);

  k_mlp<<<NB, FH, 0, stream>>>(pmax, psum, Wl1, bl1, Wl2, bl2, Wl3, bl3, out);
}